// Round 7
// baseline (636.641 us; speedup 1.0000x reference)
//
#include <hip/hip_runtime.h>
#include <cstdint>
#include <cstddef>

#define Bb 4
#define Tt 2048
#define Ssz 2048
#define Cc 256
#define Ee 512
#define Hh 8

typedef short bf8 __attribute__((ext_vector_type(8)));
typedef float f4 __attribute__((ext_vector_type(4)));
typedef float f16v __attribute__((ext_vector_type(16)));
typedef unsigned int u32x2 __attribute__((ext_vector_type(2)));
typedef unsigned int u32x4 __attribute__((ext_vector_type(4)));

__device__ __forceinline__ unsigned short f2bf(float x) {
  unsigned int u = __float_as_uint(x);
  u += 0x7fffu + ((u >> 16) & 1u);
  return (unsigned short)(u >> 16);
}

__device__ __forceinline__ bf8 cvt8(float4 a, float4 b) {
  bf8 r;
  r[0] = (short)f2bf(a.x); r[1] = (short)f2bf(a.y);
  r[2] = (short)f2bf(a.z); r[3] = (short)f2bf(a.w);
  r[4] = (short)f2bf(b.x); r[5] = (short)f2bf(b.y);
  r[6] = (short)f2bf(b.z); r[7] = (short)f2bf(b.w);
  return r;
}

// pack two f32 (bit-truncated) into one dword of 2 bf16 via v_perm_b32
#if __has_builtin(__builtin_amdgcn_perm)
#define PACK2(u0, u1) __builtin_amdgcn_perm((u1), (u0), 0x07060302u)
#else
#define PACK2(u0, u1) (((u0) >> 16) | ((u1) & 0xffff0000u))
#endif

#define EXPU(v) __float_as_uint(__builtin_amdgcn_exp2f(v))
#define MFMA32(a, b, c) __builtin_amdgcn_mfma_f32_32x32x16_bf16((a), (b), (c), 0, 0, 0)

// v_permlane32_swap_b32: a.upper32lanes <-> b.lower32lanes (dual result)
__device__ __forceinline__ void pl32swap(unsigned int& a, unsigned int& b) {
#if __has_builtin(__builtin_amdgcn_permlane32_swap)
  u32x2 r = __builtin_amdgcn_permlane32_swap(a, b, false, false);
  a = r[0];
  b = r[1];
#else
  unsigned int ax = (unsigned int)__shfl_xor((int)a, 32);
  unsigned int bx = (unsigned int)__shfl_xor((int)b, 32);
  bool hi = (threadIdx.x & 32) != 0;
  unsigned int an = hi ? bx : a;
  unsigned int bn = hi ? b : ax;
  a = an;
  b = bn;
#endif
}

// ---------------- prep: weight casts + wqin GEMM + bqin ----------------
// bid<512: wk/wv cast; <640: wo cast; <672: wqin; <688: bqin
__global__ __launch_bounds__(256) void prep(const float* __restrict__ w_in,
                                            const float* __restrict__ b_in,
                                            const float* __restrict__ wq,
                                            const float* __restrict__ bq,
                                            const float* __restrict__ wk,
                                            const float* __restrict__ wv,
                                            const float* __restrict__ wo,
                                            unsigned short* __restrict__ wkvb,
                                            unsigned short* __restrict__ wob,
                                            unsigned short* __restrict__ wqin,
                                            float* __restrict__ bqinb, float qsc) {
  __shared__ unsigned short sh[128][72];
  const int bid = blockIdx.x, tid = threadIdx.x;
  if (bid < 512) {
    int i = bid * 256 + tid;  // 0..131071
    const float* s = (i < 65536) ? wk : wv;
    int off = (i < 65536) ? i : i - 65536;
    float4 v = ((const float4*)s)[off];
    ushort4 o;
    o.x = f2bf(v.x); o.y = f2bf(v.y); o.z = f2bf(v.z); o.w = f2bf(v.w);
    ((ushort4*)wkvb)[i] = o;
  } else if (bid < 640) {
    int i = (bid - 512) * 256 + tid;  // 0..32767
    float4 v = ((const float4*)wo)[i];
    ushort4 o;
    o.x = f2bf(v.x); o.y = f2bf(v.y); o.z = f2bf(v.z); o.w = f2bf(v.w);
    ((ushort4*)wob)[i] = o;
  } else if (bid < 672) {
    // wqin[512,256] = (qsc*wq)[512,512] . w_in[512,256]
    const int idx = bid - 640;
    const int m0 = (idx & 7) * 64, n0 = (idx >> 3) * 64;
    unsigned short (*As)[72] = (unsigned short (*)[72]) & sh[0][0];
    unsigned short (*Bs)[72] = (unsigned short (*)[72]) & sh[64][0];
    const int wave = tid >> 6, lane = tid & 63;
    const int lrow = lane & 15, quad = lane >> 4;
    const int wm = (wave >> 1) * 32, wn = (wave & 1) * 32;
    const int arow = tid >> 3, ac = tid & 7;
    f4 acc[2][2];
#pragma unroll
    for (int i = 0; i < 2; i++)
#pragma unroll
      for (int j = 0; j < 2; j++) {
        f4 z = {0.f, 0.f, 0.f, 0.f};
        acc[i][j] = z;
      }
    for (int kt = 0; kt < 8; kt++) {
#pragma unroll
      for (int i = 0; i < 2; i++) {
        int row = arow + i * 32;
        const float* src = wq + (size_t)(m0 + row) * Ee + kt * 64 + ac * 8;
        float4 v0 = *(const float4*)src, v1 = *(const float4*)(src + 4);
        bf8 av;
        av[0] = (short)f2bf(v0.x * qsc); av[1] = (short)f2bf(v0.y * qsc);
        av[2] = (short)f2bf(v0.z * qsc); av[3] = (short)f2bf(v0.w * qsc);
        av[4] = (short)f2bf(v1.x * qsc); av[5] = (short)f2bf(v1.y * qsc);
        av[6] = (short)f2bf(v1.z * qsc); av[7] = (short)f2bf(v1.w * qsc);
        *(bf8*)&As[row][ac * 8] = av;
        int c = n0 + row;
        bf8 bv;
#pragma unroll
        for (int k = 0; k < 8; k++)
          bv[k] = (short)f2bf(w_in[(size_t)(kt * 64 + ac * 8 + k) * Cc + c]);
        *(bf8*)&Bs[row][ac * 8] = bv;
      }
      __syncthreads();
#pragma unroll
      for (int kk = 0; kk < 2; kk++) {
        bf8 af[2], bff[2];
#pragma unroll
        for (int i = 0; i < 2; i++) af[i] = *(const bf8*)&As[wm + i * 16 + lrow][kk * 32 + quad * 8];
#pragma unroll
        for (int j = 0; j < 2; j++) bff[j] = *(const bf8*)&Bs[wn + j * 16 + lrow][kk * 32 + quad * 8];
#pragma unroll
        for (int i = 0; i < 2; i++)
#pragma unroll
          for (int j = 0; j < 2; j++)
            acc[i][j] = __builtin_amdgcn_mfma_f32_16x16x32_bf16(af[i], bff[j], acc[i][j], 0, 0, 0);
      }
      __syncthreads();
    }
#pragma unroll
    for (int j = 0; j < 2; j++)
#pragma unroll
      for (int i = 0; i < 2; i++)
#pragma unroll
        for (int r = 0; r < 4; r++)
          wqin[(size_t)(m0 + wm + i * 16 + quad * 4 + r) * Cc + n0 + wn + j * 16 + lrow] =
              f2bf(acc[i][j][r]);
  } else {
    const int o = (bid - 672) * 32 + (tid >> 3);
    const int k0 = (tid & 7) * 64;
    float s = 0.f;
#pragma unroll
    for (int i = 0; i < 16; i++) {
      float4 w = *(const float4*)(wq + (size_t)o * Ee + k0 + i * 4);
      float4 bb = *(const float4*)(b_in + k0 + i * 4);
      s += w.x * bb.x + w.y * bb.y + w.z * bb.z + w.w * bb.w;
    }
    s += __shfl_xor(s, 1);
    s += __shfl_xor(s, 2);
    s += __shfl_xor(s, 4);
    if ((tid & 7) == 0) bqinb[o] = (s + bq[o]) * qsc;
  }
}

// ---------------- Q-GEMM + KV-GEMM + packmask, one dispatch ----------------
// K and V epilogues write MFMA FRAGMENT-ORDER layouts so attn can load
// fragments as single coalesced dwordx4 per wave (no LDS staging):
//  Kf: addr = ((bh*64 + s/32)*4 + (d%64)/16)*512 + (((d>>3)&1)*32 + s%32)*8 + d%8
//  Vf: addr = ((((bh*32 + s/64)*4 + (s>>4)&3)*2 + d/32)*512 + (((s>>3)&1)*32 + d%32)*8 + s%8
__global__ __launch_bounds__(256) void qkv(const float* __restrict__ x,
                                           const float* __restrict__ ctx,
                                           const unsigned short* __restrict__ wqin,
                                           const float* __restrict__ bqinb,
                                           const unsigned short* __restrict__ wkv,
                                           const float* __restrict__ bk,
                                           const float* __restrict__ bv,
                                           unsigned short* __restrict__ Qb,
                                           unsigned short* __restrict__ Kf,
                                           unsigned short* __restrict__ Vf,
                                           const int* __restrict__ mask,
                                           unsigned int* __restrict__ mp) {
  __shared__ unsigned short As[128][72];
  __shared__ unsigned short Bs[128][72];
  const int bid = blockIdx.x, tid = threadIdx.x;
  if (bid >= 768) {
    int i = (bid - 768) * 256 + tid;  // 0..524287
    const int4* src = (const int4*)mask + (size_t)i * 8;
    unsigned int w = 0;
#pragma unroll
    for (int k = 0; k < 8; k++) {
      int4 v = src[k];
      w |= (unsigned int)(v.x != 0) << (k * 4);
      w |= (unsigned int)(v.y != 0) << (k * 4 + 1);
      w |= (unsigned int)(v.z != 0) << (k * 4 + 2);
      w |= (unsigned int)(v.w != 0) << (k * 4 + 3);
    }
    mp[i] = w;
    return;
  }
  const bool isQ = bid < 256;
  const int idx = isQ ? bid : bid - 256;
  const int m0 = (idx & 63) * 128;
  const int n0 = (idx >> 6) * 128;
  const int K = isQ ? 256 : 512;
  const float* A = isQ ? x : ctx;
  const unsigned short* Bt = isQ ? wqin : wkv;

  const int wave = tid >> 6, lane = tid & 63;
  const int lrow = lane & 15, quad = lane >> 4;
  const int wm = (wave >> 1) * 64, wn = (wave & 1) * 64;
  const int arow = tid >> 3, ac = tid & 7;

  f4 acc[4][4];
#pragma unroll
  for (int i = 0; i < 4; i++)
#pragma unroll
    for (int j = 0; j < 4; j++) {
      f4 z = {0.f, 0.f, 0.f, 0.f};
      acc[i][j] = z;
    }

  float4 ap0[4], ap1[4];
  bf8 bpre[4];
#pragma unroll
  for (int i = 0; i < 4; i++) {
    const float* src = A + (size_t)(m0 + arow + i * 32) * K + ac * 8;
    ap0[i] = *(const float4*)src;
    ap1[i] = *(const float4*)(src + 4);
    bpre[i] = *(const bf8*)(Bt + (size_t)(n0 + arow + i * 32) * K + ac * 8);
  }

  const int nkt = K >> 6;
  for (int kt = 0; kt < nkt; ++kt) {
#pragma unroll
    for (int i = 0; i < 4; i++) {
      *(bf8*)&As[arow + i * 32][ac * 8] = cvt8(ap0[i], ap1[i]);
      *(bf8*)&Bs[arow + i * 32][ac * 8] = bpre[i];
    }
    __syncthreads();
    if (kt + 1 < nkt) {
      int k0 = (kt + 1) << 6;
#pragma unroll
      for (int i = 0; i < 4; i++) {
        const float* src = A + (size_t)(m0 + arow + i * 32) * K + k0 + ac * 8;
        ap0[i] = *(const float4*)src;
        ap1[i] = *(const float4*)(src + 4);
        bpre[i] = *(const bf8*)(Bt + (size_t)(n0 + arow + i * 32) * K + k0 + ac * 8);
      }
    }
#pragma unroll
    for (int kk = 0; kk < 2; kk++) {
      bf8 af[4], bff[4];
#pragma unroll
      for (int i = 0; i < 4; i++)
        af[i] = *(const bf8*)&As[wm + i * 16 + lrow][kk * 32 + quad * 8];
#pragma unroll
      for (int j = 0; j < 4; j++)
        bff[j] = *(const bf8*)&Bs[wn + j * 16 + lrow][kk * 32 + quad * 8];
#pragma unroll
      for (int i = 0; i < 4; i++)
#pragma unroll
        for (int j = 0; j < 4; j++)
          acc[i][j] = __builtin_amdgcn_mfma_f32_16x16x32_bf16(af[i], bff[j],
                                                              acc[i][j], 0, 0, 0);
    }
    __syncthreads();
  }

  if (isQ) {
#pragma unroll
    for (int j = 0; j < 4; j++) {
      int col = n0 + wn + j * 16 + lrow;
      float bvv = bqinb[col];
#pragma unroll
      for (int i = 0; i < 4; i++)
#pragma unroll
        for (int r = 0; r < 4; r++)
          Qb[(size_t)(m0 + wm + i * 16 + quad * 4 + r) * Ee + col] =
              f2bf(acc[i][j][r] + bvv);
    }
  } else if (n0 < 512) {  // K half -> fragment-order store
#pragma unroll
    for (int j = 0; j < 4; j++) {
      int col = n0 + wn + j * 16 + lrow;
      int h = col >> 6, dloc = col & 63;
      int cc = dloc >> 4, hh = (dloc >> 3) & 1, ee = dloc & 7;
      float bvv = bk[col];
#pragma unroll
      for (int i = 0; i < 4; i++)
#pragma unroll
        for (int r = 0; r < 4; r++) {
          int tok = m0 + wm + i * 16 + quad * 4 + r;
          int bb = tok >> 11, ss = tok & 2047;
          size_t addr = (((size_t)(bb * Hh + h) * 64 + (ss >> 5)) * 4 + cc) * 512 +
                        (hh * 32 + (ss & 31)) * 8 + ee;
          Kf[addr] = f2bf(acc[i][j][r] + bvv);
        }
    }
  } else {  // V half -> fragment-order store (ushort4 = 4 consecutive s)
#pragma unroll
    for (int j = 0; j < 4; j++) {
      int d = n0 - 512 + wn + j * 16 + lrow;
      int h = d >> 6, dd = d & 63;
      int l31 = dd & 31, dh = dd >> 5;
      float bvv = bv[d];
#pragma unroll
      for (int i = 0; i < 4; i++) {
        int tok = m0 + wm + i * 16 + quad * 4;  // 4 consecutive tokens
        int bb = tok >> 11, sl = tok & 2047;
        int stile = sl >> 6, cc = (sl >> 4) & 3, hh = (sl >> 3) & 1, e0 = sl & 7;
        ushort4 pk;
        pk.x = f2bf(acc[i][j][0] + bvv);
        pk.y = f2bf(acc[i][j][1] + bvv);
        pk.z = f2bf(acc[i][j][2] + bvv);
        pk.w = f2bf(acc[i][j][3] + bvv);
        size_t addr = ((((size_t)(bb * Hh + h) * 32 + stile) * 4 + cc) * 2 + dh) * 512 +
                      (hh * 32 + l31) * 8 + e0;
        *(ushort4*)(Vf + addr) = pk;
      }
    }
  }
}

// ---------------- GEMM: C[M,N] = A[M,K]*Bt[N,K]^T + bias (bf16 A) ----------------
template <bool OUT_BF16, int BM, int BN, int WGM>
__global__ __launch_bounds__(256) void gemm_bt(const unsigned short* __restrict__ A,
                                               const unsigned short* __restrict__ Bt,
                                               const float* __restrict__ bias0,
                                               void* __restrict__ Cout,
                                               int M, int N, int K) {
  constexpr int WGN = 4 / WGM;
  constexpr int MI = BM / (WGM * 16);
  constexpr int NJ = BN / (WGN * 16);
  constexpr int NA = BM / 32;
  constexpr int NB = BN / 32;
  __shared__ unsigned short As[BM][72];
  __shared__ unsigned short Bs[BN][72];
  const int tid = threadIdx.x;
  const int wave = tid >> 6, lane = tid & 63;
  const int lrow = lane & 15, quad = lane >> 4;
  const int wm = (wave / WGN) * (BM / WGM);
  const int wn = (wave % WGN) * (BN / WGN);
  const int m0 = blockIdx.x * BM, n0 = blockIdx.y * BN;
  const int arow = tid >> 3, ac = tid & 7;

  f4 acc[MI][NJ];
#pragma unroll
  for (int i = 0; i < MI; i++)
#pragma unroll
    for (int j = 0; j < NJ; j++) {
      f4 z = {0.f, 0.f, 0.f, 0.f};
      acc[i][j] = z;
    }

  bf8 apre[NA], bpre[NB];
#pragma unroll
  for (int i = 0; i < NA; i++)
    apre[i] = *(const bf8*)(A + (size_t)(m0 + arow + i * 32) * K + ac * 8);
#pragma unroll
  for (int i = 0; i < NB; i++)
    bpre[i] = *(const bf8*)(Bt + (size_t)(n0 + arow + i * 32) * K + ac * 8);

  const int nkt = K >> 6;
  for (int kt = 0; kt < nkt; ++kt) {
#pragma unroll
    for (int i = 0; i < NA; i++) *(bf8*)&As[arow + i * 32][ac * 8] = apre[i];
#pragma unroll
    for (int i = 0; i < NB; i++) *(bf8*)&Bs[arow + i * 32][ac * 8] = bpre[i];
    __syncthreads();
    if (kt + 1 < nkt) {
      int k0 = (kt + 1) << 6;
#pragma unroll
      for (int i = 0; i < NA; i++)
        apre[i] = *(const bf8*)(A + (size_t)(m0 + arow + i * 32) * K + k0 + ac * 8);
#pragma unroll
      for (int i = 0; i < NB; i++)
        bpre[i] = *(const bf8*)(Bt + (size_t)(n0 + arow + i * 32) * K + k0 + ac * 8);
    }
#pragma unroll
    for (int kk = 0; kk < 2; kk++) {
      bf8 af[MI], bff[NJ];
#pragma unroll
      for (int i = 0; i < MI; i++)
        af[i] = *(const bf8*)&As[wm + i * 16 + lrow][kk * 32 + quad * 8];
#pragma unroll
      for (int j = 0; j < NJ; j++)
        bff[j] = *(const bf8*)&Bs[wn + j * 16 + lrow][kk * 32 + quad * 8];
#pragma unroll
      for (int i = 0; i < MI; i++)
#pragma unroll
        for (int j = 0; j < NJ; j++)
          acc[i][j] = __builtin_amdgcn_mfma_f32_16x16x32_bf16(af[i], bff[j],
                                                              acc[i][j], 0, 0, 0);
    }
    __syncthreads();
  }

#pragma unroll
  for (int j = 0; j < NJ; j++) {
    int col = n0 + wn + j * 16 + lrow;
    float bvv = bias0 ? bias0[col] : 0.f;
#pragma unroll
    for (int i = 0; i < MI; i++) {
#pragma unroll
      for (int r = 0; r < 4; r++) {
        int row = m0 + wm + i * 16 + quad * 4 + r;
        float v = acc[i][j][r] + bvv;
        if (OUT_BF16)
          ((unsigned short*)Cout)[(size_t)row * N + col] = f2bf(v);
        else
          ((float*)Cout)[(size_t)row * N + col] = v;
      }
    }
  }
}

// ---------------- fused masked cross-attention (in-block split-S, 4 waves/SIMD) ---
// Evidence: R3/R6 both sit at elapsed/iter ~= MFMA-issue / 0.27 with no pipe
// >40% busy -> within-wave dependency-chain latency at 2 waves/SIMD is the
// limiter. R4: in-wave ILP doesn't fix it. R5: 4 waves/SIMD works ONLY if
// memory traffic doesn't grow (its partial-O HBM writes + cross-block L2
// thrash cost more than the TLP gained). This version doubles waves/SIMD with
// BYTE-IDENTICAL global traffic: 512-thread blocks, waves 0-3 take s<1024,
// waves 4-7 take s>=1024 for the SAME 128 t; partials merge in-block through
// LDS (f32, one barrier, one-time ~1us) and O is written once. Frag-direct
// body from R6 (no staging, no per-iter barriers). Grid 512 x 2 blocks/CU ->
// 16 waves/CU = 4 waves/SIMD.
__global__ __launch_bounds__(512, 4) void attn(const unsigned short* __restrict__ Q,
                                               const unsigned short* __restrict__ Kf,
                                               const unsigned short* __restrict__ Vf,
                                               const unsigned int* __restrict__ mp,
                                               unsigned short* __restrict__ O) {
  __shared__ float mbuf[4][64][48];  // [wsub][lane][oacc0 16 | oacc1 16 | dacc 16]
  const int tid = threadIdx.x;
  const int wave = tid >> 6, lane = tid & 63;
  const int l31 = lane & 31, hi = lane >> 5;
  const int wsub = wave & 3, shh = wave >> 2;  // shh = s-half
  const int bid = blockIdx.x;
  const int bh = bid & 31, b = bh >> 3, h = bh & 7;
  const int t0 = (bid >> 5) * 128;
  const int tw = t0 + wsub * 32;
  const int sbase = shh << 10;

  // Q B-frags: lane (t=l31, hi) holds Q[t][c*16 + hi*8 .. +8]
  const unsigned short* Qrow =
      Q + (size_t)(b * Tt + tw + l31) * Ee + h * 64 + hi * 8;
  bf8 qf[4];
#pragma unroll
  for (int c = 0; c < 4; c++) qf[c] = *(const bf8*)(Qrow + c * 16);

  f16v oacc0, oacc1, dacc;
#pragma unroll
  for (int r = 0; r < 16; r++) {
    oacc0[r] = 0.f;
    oacc1[r] = 0.f;
    dacc[r] = 0.f;
  }
  bf8 ones;
#pragma unroll
  for (int k = 0; k < 8; k++) ones[k] = (short)0x3F80;  // bf16 1.0

  // per-lane fragment bases (fragment-order layout, L2-resident, XCD-local)
  const unsigned short* Kl = Kf + (size_t)bh * 131072 + lane * 8;
  const unsigned short* Vl = Vf + (size_t)bh * 131072 + lane * 8;
  const unsigned int* mroww = mp + (size_t)(b * Tt + tw + l31) * 64;

  bf8 ka[2][4], kb[2][4];  // double-buffered K-frags [sblk][c]

  auto pfk = [&](bf8 (&KD)[2][4], int s0) {
#pragma unroll
    for (int sb = 0; sb < 2; sb++)
#pragma unroll
      for (int c = 0; c < 4; c++)
        KD[sb][c] = *(const bf8*)(Kl + (((((s0 >> 5) + sb) * 4) + c) << 9));
  };

  auto body = [&](bf8 (&KF)[2][4], bf8 (&KN)[2][4], int s0, bool dopf) {
    // V-frags for this tile: latency hidden under mask-init + score phase
    bf8 vf[4][2];
#pragma unroll
    for (int c = 0; c < 4; c++)
#pragma unroll
      for (int dh = 0; dh < 2; dh++)
        vf[c][dh] = *(const bf8*)(Vl + (((((s0 >> 6) * 4 + c) * 2) + dh) << 9));
    const uint2 mw = *(const uint2*)(mroww + (s0 >> 5));
    const unsigned int wsh0 = mw.x >> (4 * hi);
    const unsigned int wsh1 = mw.y >> (4 * hi);

    // mask pre-init: sa row s=(r&3)+8*(r>>2)+4*hi (+32 for sa1), col t=l31
    f16v sa0, sa1;
#pragma unroll
    for (int r = 0; r < 16; r++) {
      const int shft = (r & 3) + 8 * (r >> 2);
      sa0[r] = ((wsh0 >> shft) & 1u) ? -1e9f : 0.f;
      sa1[r] = ((wsh1 >> shft) & 1u) ? -1e9f : 0.f;
    }
    // scores: S^T = K . Q^T  (two 32s x 32t blocks, k=d in 4 chunks of 16)
    __builtin_amdgcn_s_setprio(1);
#pragma unroll
    for (int c = 0; c < 4; c++) {
      sa0 = MFMA32(KF[0][c], qf[c], sa0);
      sa1 = MFMA32(KF[1][c], qf[c], sa1);
    }
    __builtin_amdgcn_s_setprio(0);
    // next-iter K prefetch: latency hidden under exp/pack + PV
    if (dopf) pfk(KN, s0 + 64);
    // exp2 + pack pairs (truncating bf16)
    unsigned int X0[8], X1[8];
#pragma unroll
    for (int m = 0; m < 8; m++) {
      X0[m] = PACK2(EXPU(sa0[2 * m]), EXPU(sa0[2 * m + 1]));
      X1[m] = PACK2(EXPU(sa1[2 * m]), EXPU(sa1[2 * m + 1]));
    }
    // lane^32 exchange -> PV A-frags pa[c]: lane holds P[t=l31][s=c*16+hi*8..+8]
    __builtin_amdgcn_s_setprio(1);
#pragma unroll
    for (int c = 0; c < 4; c++) {
      const int m0 = 4 * (c & 1);
      unsigned int a0, a1, a2, a3;
      if (c < 2) {
        a0 = X0[m0]; a1 = X0[m0 + 1]; a2 = X0[m0 + 2]; a3 = X0[m0 + 3];
      } else {
        a0 = X1[m0]; a1 = X1[m0 + 1]; a2 = X1[m0 + 2]; a3 = X1[m0 + 3];
      }
      pl32swap(a0, a2);  // -> dwords j=0, j=2
      pl32swap(a1, a3);  // -> dwords j=1, j=3
      u32x4 pdv;
      pdv[0] = a0; pdv[1] = a1; pdv[2] = a2; pdv[3] = a3;
      bf8 pa = *(bf8*)&pdv;
      dacc = MFMA32(pa, ones, dacc);
      oacc0 = MFMA32(pa, vf[c][0], oacc0);
      oacc1 = MFMA32(pa, vf[c][1], oacc1);
    }
    __builtin_amdgcn_s_setprio(0);
  };

  pfk(ka, sbase);
  for (int s0 = sbase; s0 < sbase + 1024; s0 += 128) {
    body(ka, kb, s0, true);
    body(kb, ka, s0 + 64, s0 + 128 < sbase + 1024);
  }

  // in-block merge: s-half 1 publishes f32 partials; s-half 0 merges + stores
  if (shh) {
#pragma unroll
    for (int q = 0; q < 4; q++) {
      float4 v0 = {oacc0[4 * q], oacc0[4 * q + 1], oacc0[4 * q + 2], oacc0[4 * q + 3]};
      float4 v1 = {oacc1[4 * q], oacc1[4 * q + 1], oacc1[4 * q + 2], oacc1[4 * q + 3]};
      float4 v2 = {dacc[4 * q], dacc[4 * q + 1], dacc[4 * q + 2], dacc[4 * q + 3]};
      *(float4*)&mbuf[wsub][lane][4 * q] = v0;
      *(float4*)&mbuf[wsub][lane][16 + 4 * q] = v1;
      *(float4*)&mbuf[wsub][lane][32 + 4 * q] = v2;
    }
  }
  __syncthreads();
  if (!shh) {
    // epilogue: O row t = (r&3)+8*(r>>2)+4*hi, col d = dblk*32 + l31
#pragma unroll
    for (int r = 0; r < 16; r++) {
      const int tl = (r & 3) + 8 * (r >> 2) + 4 * hi;
      const float inv = 1.0f / (dacc[r] + mbuf[wsub][lane][32 + r]);
      const size_t off = (size_t)(b * Tt + tw + tl) * Ee + h * 64 + l31;
      O[off] = f2bf((oacc0[r] + mbuf[wsub][lane][r]) * inv);
      O[off + 32] = f2bf((oacc1[r] + mbuf[wsub][lane][16 + r]) * inv);
    }
  }
}

// ---------------- launcher ----------------
extern "C" void kernel_launch(void* const* d_in, const int* in_sizes, int n_in,
                              void* d_out, int out_size, void* d_ws, size_t ws_size,
                              hipStream_t stream) {
  const float* x    = (const float*)d_in[0];
  const float* ctx  = (const float*)d_in[1];
  const int*   mask = (const int*)d_in[2];
  const float* w_in = (const float*)d_in[3];
  const float* b_in = (const float*)d_in[4];
  const float* wq   = (const float*)d_in[5];
  const float* bq   = (const float*)d_in[6];
  const float* wk   = (const float*)d_in[7];
  const float* bk   = (const float*)d_in[8];
  const float* wv   = (const float*)d_in[9];
  const float* bv   = (const float*)d_in[10];
  const float* wo   = (const float*)d_in[11];
  const float* bo   = (const float*)d_in[12];

  const float qsc = 0.04419417382415922f * 1.4426950408889634f;  // E^-0.5 * log2(e)

  unsigned short* ws = (unsigned short*)d_ws;
  unsigned int*   maskp = (unsigned int*)ws;        // [4*2048*64] = 2MB
  unsigned short* wkvb  = ws + 1048576;             // [1024,512]
  unsigned short* wob   = ws + 1572864;             // [256,512]
  unsigned short* wqin  = ws + 1703936;             // [512,256]
  float*          bqinb = (float*)(ws + 1835008);   // [512]
  unsigned short* Qb    = ws + 1836032;             // [8192,512]
  unsigned short* Kfb   = ws + 6030336;             // K fragment-order [32bh][131072]
  unsigned short* Vfb   = ws + 10224640;            // V fragment-order [32bh][131072]
  unsigned short* Ob    = ws + 14418944;            // [8192,512]

  prep<<<688, 256, 0, stream>>>(w_in, b_in, wq, bq, wk, wv, wo,
                                wkvb, wob, wqin, bqinb, qsc);
  qkv<<<2816, 256, 0, stream>>>(x, ctx, wqin, bqinb, wkvb, bk, bv, Qb, Kfb, Vfb,
                                mask, maskp);
  attn<<<512, 512, 0, stream>>>(Qb, Kfb, Vfb, maskp, Ob);
  gemm_bt<false, 64, 64, 2><<<dim3(128, 4), 256, 0, stream>>>(
      Ob, wob, bo, d_out, 8192, 256, 512);
}

// Round 8
// 240.917 us; speedup vs baseline: 2.6426x; 2.6426x over previous
//
#include <hip/hip_runtime.h>
#include <cstdint>
#include <cstddef>

#define Bb 4
#define Tt 2048
#define Ssz 2048
#define Cc 256
#define Ee 512
#define Hh 8

typedef short bf8 __attribute__((ext_vector_type(8)));
typedef float f4 __attribute__((ext_vector_type(4)));
typedef float f16v __attribute__((ext_vector_type(16)));
typedef unsigned int u32x2 __attribute__((ext_vector_type(2)));
typedef unsigned int u32x4 __attribute__((ext_vector_type(4)));

__device__ __forceinline__ unsigned short f2bf(float x) {
  unsigned int u = __float_as_uint(x);
  u += 0x7fffu + ((u >> 16) & 1u);
  return (unsigned short)(u >> 16);
}

__device__ __forceinline__ bf8 cvt8(float4 a, float4 b) {
  bf8 r;
  r[0] = (short)f2bf(a.x); r[1] = (short)f2bf(a.y);
  r[2] = (short)f2bf(a.z); r[3] = (short)f2bf(a.w);
  r[4] = (short)f2bf(b.x); r[5] = (short)f2bf(b.y);
  r[6] = (short)f2bf(b.z); r[7] = (short)f2bf(b.w);
  return r;
}

// pack two f32 (bit-truncated) into one dword of 2 bf16 via v_perm_b32
#if __has_builtin(__builtin_amdgcn_perm)
#define PACK2(u0, u1) __builtin_amdgcn_perm((u1), (u0), 0x07060302u)
#else
#define PACK2(u0, u1) (((u0) >> 16) | ((u1) & 0xffff0000u))
#endif

#define EXPU(v) __float_as_uint(__builtin_amdgcn_exp2f(v))
#define MFMA32(a, b, c) __builtin_amdgcn_mfma_f32_32x32x16_bf16((a), (b), (c), 0, 0, 0)

// v_permlane32_swap_b32: a.upper32lanes <-> b.lower32lanes (dual result)
__device__ __forceinline__ void pl32swap(unsigned int& a, unsigned int& b) {
#if __has_builtin(__builtin_amdgcn_permlane32_swap)
  u32x2 r = __builtin_amdgcn_permlane32_swap(a, b, false, false);
  a = r[0];
  b = r[1];
#else
  unsigned int ax = (unsigned int)__shfl_xor((int)a, 32);
  unsigned int bx = (unsigned int)__shfl_xor((int)b, 32);
  bool hi = (threadIdx.x & 32) != 0;
  unsigned int an = hi ? bx : a;
  unsigned int bn = hi ? b : ax;
  a = an;
  b = bn;
#endif
}

// ---------------- prep: weight casts + wqin GEMM + bqin ----------------
// bid<512: wk/wv cast; <640: wo cast; <672: wqin; <688: bqin
__global__ __launch_bounds__(256) void prep(const float* __restrict__ w_in,
                                            const float* __restrict__ b_in,
                                            const float* __restrict__ wq,
                                            const float* __restrict__ bq,
                                            const float* __restrict__ wk,
                                            const float* __restrict__ wv,
                                            const float* __restrict__ wo,
                                            unsigned short* __restrict__ wkvb,
                                            unsigned short* __restrict__ wob,
                                            unsigned short* __restrict__ wqin,
                                            float* __restrict__ bqinb, float qsc) {
  __shared__ unsigned short sh[128][72];
  const int bid = blockIdx.x, tid = threadIdx.x;
  if (bid < 512) {
    int i = bid * 256 + tid;  // 0..131071
    const float* s = (i < 65536) ? wk : wv;
    int off = (i < 65536) ? i : i - 65536;
    float4 v = ((const float4*)s)[off];
    ushort4 o;
    o.x = f2bf(v.x); o.y = f2bf(v.y); o.z = f2bf(v.z); o.w = f2bf(v.w);
    ((ushort4*)wkvb)[i] = o;
  } else if (bid < 640) {
    int i = (bid - 512) * 256 + tid;  // 0..32767
    float4 v = ((const float4*)wo)[i];
    ushort4 o;
    o.x = f2bf(v.x); o.y = f2bf(v.y); o.z = f2bf(v.z); o.w = f2bf(v.w);
    ((ushort4*)wob)[i] = o;
  } else if (bid < 672) {
    // wqin[512,256] = (qsc*wq)[512,512] . w_in[512,256]
    const int idx = bid - 640;
    const int m0 = (idx & 7) * 64, n0 = (idx >> 3) * 64;
    unsigned short (*As)[72] = (unsigned short (*)[72]) & sh[0][0];
    unsigned short (*Bs)[72] = (unsigned short (*)[72]) & sh[64][0];
    const int wave = tid >> 6, lane = tid & 63;
    const int lrow = lane & 15, quad = lane >> 4;
    const int wm = (wave >> 1) * 32, wn = (wave & 1) * 32;
    const int arow = tid >> 3, ac = tid & 7;
    f4 acc[2][2];
#pragma unroll
    for (int i = 0; i < 2; i++)
#pragma unroll
      for (int j = 0; j < 2; j++) {
        f4 z = {0.f, 0.f, 0.f, 0.f};
        acc[i][j] = z;
      }
    for (int kt = 0; kt < 8; kt++) {
#pragma unroll
      for (int i = 0; i < 2; i++) {
        int row = arow + i * 32;
        const float* src = wq + (size_t)(m0 + row) * Ee + kt * 64 + ac * 8;
        float4 v0 = *(const float4*)src, v1 = *(const float4*)(src + 4);
        bf8 av;
        av[0] = (short)f2bf(v0.x * qsc); av[1] = (short)f2bf(v0.y * qsc);
        av[2] = (short)f2bf(v0.z * qsc); av[3] = (short)f2bf(v0.w * qsc);
        av[4] = (short)f2bf(v1.x * qsc); av[5] = (short)f2bf(v1.y * qsc);
        av[6] = (short)f2bf(v1.z * qsc); av[7] = (short)f2bf(v1.w * qsc);
        *(bf8*)&As[row][ac * 8] = av;
        int c = n0 + row;
        bf8 bv;
#pragma unroll
        for (int k = 0; k < 8; k++)
          bv[k] = (short)f2bf(w_in[(size_t)(kt * 64 + ac * 8 + k) * Cc + c]);
        *(bf8*)&Bs[row][ac * 8] = bv;
      }
      __syncthreads();
#pragma unroll
      for (int kk = 0; kk < 2; kk++) {
        bf8 af[2], bff[2];
#pragma unroll
        for (int i = 0; i < 2; i++) af[i] = *(const bf8*)&As[wm + i * 16 + lrow][kk * 32 + quad * 8];
#pragma unroll
        for (int j = 0; j < 2; j++) bff[j] = *(const bf8*)&Bs[wn + j * 16 + lrow][kk * 32 + quad * 8];
#pragma unroll
        for (int i = 0; i < 2; i++)
#pragma unroll
          for (int j = 0; j < 2; j++)
            acc[i][j] = __builtin_amdgcn_mfma_f32_16x16x32_bf16(af[i], bff[j], acc[i][j], 0, 0, 0);
      }
      __syncthreads();
    }
#pragma unroll
    for (int j = 0; j < 2; j++)
#pragma unroll
      for (int i = 0; i < 2; i++)
#pragma unroll
        for (int r = 0; r < 4; r++)
          wqin[(size_t)(m0 + wm + i * 16 + quad * 4 + r) * Cc + n0 + wn + j * 16 + lrow] =
              f2bf(acc[i][j][r]);
  } else {
    const int o = (bid - 672) * 32 + (tid >> 3);
    const int k0 = (tid & 7) * 64;
    float s = 0.f;
#pragma unroll
    for (int i = 0; i < 16; i++) {
      float4 w = *(const float4*)(wq + (size_t)o * Ee + k0 + i * 4);
      float4 bb = *(const float4*)(b_in + k0 + i * 4);
      s += w.x * bb.x + w.y * bb.y + w.z * bb.z + w.w * bb.w;
    }
    s += __shfl_xor(s, 1);
    s += __shfl_xor(s, 2);
    s += __shfl_xor(s, 4);
    if ((tid & 7) == 0) bqinb[o] = (s + bq[o]) * qsc;
  }
}

// ---------------- Q-GEMM + KV-GEMM + packmask, one dispatch ----------------
// K and V epilogues write MFMA FRAGMENT-ORDER layouts so attn can load
// fragments as single coalesced dwordx4 per wave (no LDS staging):
//  Kf: addr = ((bh*64 + s/32)*4 + (d%64)/16)*512 + (((d>>3)&1)*32 + s%32)*8 + d%8
//  Vf: addr = ((((bh*32 + s/64)*4 + (s>>4)&3)*2 + d/32)*512 + (((s>>3)&1)*32 + d%32)*8 + s%8
__global__ __launch_bounds__(256) void qkv(const float* __restrict__ x,
                                           const float* __restrict__ ctx,
                                           const unsigned short* __restrict__ wqin,
                                           const float* __restrict__ bqinb,
                                           const unsigned short* __restrict__ wkv,
                                           const float* __restrict__ bk,
                                           const float* __restrict__ bv,
                                           unsigned short* __restrict__ Qb,
                                           unsigned short* __restrict__ Kf,
                                           unsigned short* __restrict__ Vf,
                                           const int* __restrict__ mask,
                                           unsigned int* __restrict__ mp) {
  __shared__ unsigned short As[128][72];
  __shared__ unsigned short Bs[128][72];
  const int bid = blockIdx.x, tid = threadIdx.x;
  if (bid >= 768) {
    int i = (bid - 768) * 256 + tid;  // 0..524287
    const int4* src = (const int4*)mask + (size_t)i * 8;
    unsigned int w = 0;
#pragma unroll
    for (int k = 0; k < 8; k++) {
      int4 v = src[k];
      w |= (unsigned int)(v.x != 0) << (k * 4);
      w |= (unsigned int)(v.y != 0) << (k * 4 + 1);
      w |= (unsigned int)(v.z != 0) << (k * 4 + 2);
      w |= (unsigned int)(v.w != 0) << (k * 4 + 3);
    }
    mp[i] = w;
    return;
  }
  const bool isQ = bid < 256;
  const int idx = isQ ? bid : bid - 256;
  const int m0 = (idx & 63) * 128;
  const int n0 = (idx >> 6) * 128;
  const int K = isQ ? 256 : 512;
  const float* A = isQ ? x : ctx;
  const unsigned short* Bt = isQ ? wqin : wkv;

  const int wave = tid >> 6, lane = tid & 63;
  const int lrow = lane & 15, quad = lane >> 4;
  const int wm = (wave >> 1) * 64, wn = (wave & 1) * 64;
  const int arow = tid >> 3, ac = tid & 7;

  f4 acc[4][4];
#pragma unroll
  for (int i = 0; i < 4; i++)
#pragma unroll
    for (int j = 0; j < 4; j++) {
      f4 z = {0.f, 0.f, 0.f, 0.f};
      acc[i][j] = z;
    }

  float4 ap0[4], ap1[4];
  bf8 bpre[4];
#pragma unroll
  for (int i = 0; i < 4; i++) {
    const float* src = A + (size_t)(m0 + arow + i * 32) * K + ac * 8;
    ap0[i] = *(const float4*)src;
    ap1[i] = *(const float4*)(src + 4);
    bpre[i] = *(const bf8*)(Bt + (size_t)(n0 + arow + i * 32) * K + ac * 8);
  }

  const int nkt = K >> 6;
  for (int kt = 0; kt < nkt; ++kt) {
#pragma unroll
    for (int i = 0; i < 4; i++) {
      *(bf8*)&As[arow + i * 32][ac * 8] = cvt8(ap0[i], ap1[i]);
      *(bf8*)&Bs[arow + i * 32][ac * 8] = bpre[i];
    }
    __syncthreads();
    if (kt + 1 < nkt) {
      int k0 = (kt + 1) << 6;
#pragma unroll
      for (int i = 0; i < 4; i++) {
        const float* src = A + (size_t)(m0 + arow + i * 32) * K + k0 + ac * 8;
        ap0[i] = *(const float4*)src;
        ap1[i] = *(const float4*)(src + 4);
        bpre[i] = *(const bf8*)(Bt + (size_t)(n0 + arow + i * 32) * K + k0 + ac * 8);
      }
    }
#pragma unroll
    for (int kk = 0; kk < 2; kk++) {
      bf8 af[4], bff[4];
#pragma unroll
      for (int i = 0; i < 4; i++)
        af[i] = *(const bf8*)&As[wm + i * 16 + lrow][kk * 32 + quad * 8];
#pragma unroll
      for (int j = 0; j < 4; j++)
        bff[j] = *(const bf8*)&Bs[wn + j * 16 + lrow][kk * 32 + quad * 8];
#pragma unroll
      for (int i = 0; i < 4; i++)
#pragma unroll
        for (int j = 0; j < 4; j++)
          acc[i][j] = __builtin_amdgcn_mfma_f32_16x16x32_bf16(af[i], bff[j],
                                                              acc[i][j], 0, 0, 0);
    }
    __syncthreads();
  }

  if (isQ) {
#pragma unroll
    for (int j = 0; j < 4; j++) {
      int col = n0 + wn + j * 16 + lrow;
      float bvv = bqinb[col];
#pragma unroll
      for (int i = 0; i < 4; i++)
#pragma unroll
        for (int r = 0; r < 4; r++)
          Qb[(size_t)(m0 + wm + i * 16 + quad * 4 + r) * Ee + col] =
              f2bf(acc[i][j][r] + bvv);
    }
  } else if (n0 < 512) {  // K half -> fragment-order store
#pragma unroll
    for (int j = 0; j < 4; j++) {
      int col = n0 + wn + j * 16 + lrow;
      int h = col >> 6, dloc = col & 63;
      int cc = dloc >> 4, hh = (dloc >> 3) & 1, ee = dloc & 7;
      float bvv = bk[col];
#pragma unroll
      for (int i = 0; i < 4; i++)
#pragma unroll
        for (int r = 0; r < 4; r++) {
          int tok = m0 + wm + i * 16 + quad * 4 + r;
          int bb = tok >> 11, ss = tok & 2047;
          size_t addr = (((size_t)(bb * Hh + h) * 64 + (ss >> 5)) * 4 + cc) * 512 +
                        (hh * 32 + (ss & 31)) * 8 + ee;
          Kf[addr] = f2bf(acc[i][j][r] + bvv);
        }
    }
  } else {  // V half -> fragment-order store (ushort4 = 4 consecutive s)
#pragma unroll
    for (int j = 0; j < 4; j++) {
      int d = n0 - 512 + wn + j * 16 + lrow;
      int h = d >> 6, dd = d & 63;
      int l31 = dd & 31, dh = dd >> 5;
      float bvv = bv[d];
#pragma unroll
      for (int i = 0; i < 4; i++) {
        int tok = m0 + wm + i * 16 + quad * 4;  // 4 consecutive tokens
        int bb = tok >> 11, sl = tok & 2047;
        int stile = sl >> 6, cc = (sl >> 4) & 3, hh = (sl >> 3) & 1, e0 = sl & 7;
        ushort4 pk;
        pk.x = f2bf(acc[i][j][0] + bvv);
        pk.y = f2bf(acc[i][j][1] + bvv);
        pk.z = f2bf(acc[i][j][2] + bvv);
        pk.w = f2bf(acc[i][j][3] + bvv);
        size_t addr = ((((size_t)(bb * Hh + h) * 32 + stile) * 4 + cc) * 2 + dh) * 512 +
                      (hh * 32 + l31) * 8 + e0;
        *(ushort4*)(Vf + addr) = pk;
      }
    }
  }
}

// ---------------- GEMM: C[M,N] = A[M,K]*Bt[N,K]^T + bias (bf16 A) ----------------
template <bool OUT_BF16, int BM, int BN, int WGM>
__global__ __launch_bounds__(256) void gemm_bt(const unsigned short* __restrict__ A,
                                               const unsigned short* __restrict__ Bt,
                                               const float* __restrict__ bias0,
                                               void* __restrict__ Cout,
                                               int M, int N, int K) {
  constexpr int WGN = 4 / WGM;
  constexpr int MI = BM / (WGM * 16);
  constexpr int NJ = BN / (WGN * 16);
  constexpr int NA = BM / 32;
  constexpr int NB = BN / 32;
  __shared__ unsigned short As[BM][72];
  __shared__ unsigned short Bs[BN][72];
  const int tid = threadIdx.x;
  const int wave = tid >> 6, lane = tid & 63;
  const int lrow = lane & 15, quad = lane >> 4;
  const int wm = (wave / WGN) * (BM / WGM);
  const int wn = (wave % WGN) * (BN / WGN);
  const int m0 = blockIdx.x * BM, n0 = blockIdx.y * BN;
  const int arow = tid >> 3, ac = tid & 7;

  f4 acc[MI][NJ];
#pragma unroll
  for (int i = 0; i < MI; i++)
#pragma unroll
    for (int j = 0; j < NJ; j++) {
      f4 z = {0.f, 0.f, 0.f, 0.f};
      acc[i][j] = z;
    }

  bf8 apre[NA], bpre[NB];
#pragma unroll
  for (int i = 0; i < NA; i++)
    apre[i] = *(const bf8*)(A + (size_t)(m0 + arow + i * 32) * K + ac * 8);
#pragma unroll
  for (int i = 0; i < NB; i++)
    bpre[i] = *(const bf8*)(Bt + (size_t)(n0 + arow + i * 32) * K + ac * 8);

  const int nkt = K >> 6;
  for (int kt = 0; kt < nkt; ++kt) {
#pragma unroll
    for (int i = 0; i < NA; i++) *(bf8*)&As[arow + i * 32][ac * 8] = apre[i];
#pragma unroll
    for (int i = 0; i < NB; i++) *(bf8*)&Bs[arow + i * 32][ac * 8] = bpre[i];
    __syncthreads();
    if (kt + 1 < nkt) {
      int k0 = (kt + 1) << 6;
#pragma unroll
      for (int i = 0; i < NA; i++)
        apre[i] = *(const bf8*)(A + (size_t)(m0 + arow + i * 32) * K + k0 + ac * 8);
#pragma unroll
      for (int i = 0; i < NB; i++)
        bpre[i] = *(const bf8*)(Bt + (size_t)(n0 + arow + i * 32) * K + k0 + ac * 8);
    }
#pragma unroll
    for (int kk = 0; kk < 2; kk++) {
      bf8 af[MI], bff[NJ];
#pragma unroll
      for (int i = 0; i < MI; i++)
        af[i] = *(const bf8*)&As[wm + i * 16 + lrow][kk * 32 + quad * 8];
#pragma unroll
      for (int j = 0; j < NJ; j++)
        bff[j] = *(const bf8*)&Bs[wn + j * 16 + lrow][kk * 32 + quad * 8];
#pragma unroll
      for (int i = 0; i < MI; i++)
#pragma unroll
        for (int j = 0; j < NJ; j++)
          acc[i][j] = __builtin_amdgcn_mfma_f32_16x16x32_bf16(af[i], bff[j],
                                                              acc[i][j], 0, 0, 0);
    }
    __syncthreads();
  }

#pragma unroll
  for (int j = 0; j < NJ; j++) {
    int col = n0 + wn + j * 16 + lrow;
    float bvv = bias0 ? bias0[col] : 0.f;
#pragma unroll
    for (int i = 0; i < MI; i++) {
#pragma unroll
      for (int r = 0; r < 4; r++) {
        int row = m0 + wm + i * 16 + quad * 4 + r;
        float v = acc[i][j][r] + bvv;
        if (OUT_BF16)
          ((unsigned short*)Cout)[(size_t)row * N + col] = f2bf(v);
        else
          ((float*)Cout)[(size_t)row * N + col] = v;
      }
    }
  }
}

// ---------------- fused masked cross-attention (cross-iter software pipeline) -----
// Calibrated model (R3/R4/R6): per-wave critical path ~4460cy/iter = phase-
// serial {score chain 4x~300 + exp/pack ~500-900 + PV chain 4x~300}; pipes all
// <45% busy; occupancy is capped at 2-3 waves/SIMD by the ~200-reg footprint
// (R5/R7: asking for more converts to HBM-visible spills/thrash). This version
// breaks the phase serialization ACROSS iterations (T15/flash-style): carry
// sa(n) (scores of tile n) in registers; iteration n = {issue V(n), K(n+1),
// mask(n+1) loads; exp/pack sa(n)->pa; re-init sa from mask(n+1); one merged
// MFMA cluster PV(n) || scores(n+1) (5 independent chains)}. Carried cycle =
// mfma-tail + exp + init + score-chain ~= 2000cy/iter (vs 4460). Frag-order
// global K/V (R6 layout): no LDS, no barriers, loads issue >=500cy pre-use.
// ~220 regs -> launch_bounds(256,2), NO spill (watch WRITE_SIZE).
__global__ __launch_bounds__(256, 2) void attn(const unsigned short* __restrict__ Q,
                                               const unsigned short* __restrict__ Kf,
                                               const unsigned short* __restrict__ Vf,
                                               const unsigned int* __restrict__ mp,
                                               unsigned short* __restrict__ O) {
  const int tid = threadIdx.x;
  const int wave = tid >> 6, lane = tid & 63;
  const int l31 = lane & 31, hi = lane >> 5;
  const int bid = blockIdx.x;
  const int bh = bid & 31, b = bh >> 3, h = bh & 7;
  const int t0 = (bid >> 5) * 128;
  const int wm = wave * 32;

  // Q B-frags: lane (t=l31, hi) holds Q[t][c*16 + hi*8 .. +8]
  const unsigned short* Qrow =
      Q + (size_t)(b * Tt + t0 + wm + l31) * Ee + h * 64 + hi * 8;
  bf8 qf[4];
#pragma unroll
  for (int c = 0; c < 4; c++) qf[c] = *(const bf8*)(Qrow + c * 16);

  f16v oacc0, oacc1, dacc;
#pragma unroll
  for (int r = 0; r < 16; r++) {
    oacc0[r] = 0.f;
    oacc1[r] = 0.f;
    dacc[r] = 0.f;
  }
  bf8 ones;
#pragma unroll
  for (int k = 0; k < 8; k++) ones[k] = (short)0x3F80;  // bf16 1.0

  // per-lane fragment bases (fragment-order layout, L2-resident, XCD-local)
  const unsigned short* Kl = Kf + (size_t)bh * 131072 + lane * 8;
  const unsigned short* Vl = Vf + (size_t)bh * 131072 + lane * 8;
  const unsigned int* mroww = mp + (size_t)(b * Tt + t0 + wm + l31) * 64;

  bf8 kf[2][4];   // single-buffered K-frags (consumed at cluster end, reloaded next iter top)
  f16v sa0, sa1;  // carried scores S^T for the current tile

  // ---- prologue: K(0), mask(0), scores(0) ----
#pragma unroll
  for (int sb = 0; sb < 2; sb++)
#pragma unroll
    for (int c = 0; c < 4; c++)
      kf[sb][c] = *(const bf8*)(Kl + ((size_t)(sb * 4 + c) << 9));
  {
    const uint2 mw = *(const uint2*)(mroww);
    const unsigned int w0 = mw.x >> (4 * hi);
    const unsigned int w1 = mw.y >> (4 * hi);
#pragma unroll
    for (int r = 0; r < 16; r++) {
      const int sh = (r & 3) + 8 * (r >> 2);
      sa0[r] = ((w0 >> sh) & 1u) ? -1e9f : 0.f;
      sa1[r] = ((w1 >> sh) & 1u) ? -1e9f : 0.f;
    }
#pragma unroll
    for (int c = 0; c < 4; c++) {
      sa0 = MFMA32(kf[0][c], qf[c], sa0);
      sa1 = MFMA32(kf[1][c], qf[c], sa1);
    }
  }

  // ---- pipelined main loop: iter n = PV(n) + scores(n+1) ----
  for (int n = 0; n < 32; n++) {
    // issue V(n) (used ~500cy later in this iter's PV)
    bf8 vf[4][2];
#pragma unroll
    for (int c = 0; c < 4; c++)
#pragma unroll
      for (int dh = 0; dh < 2; dh++)
        vf[c][dh] = *(const bf8*)(Vl + ((size_t)((n * 4 + c) * 2 + dh) << 9));
    // issue K(n+1) + mask(n+1) (used at cluster end / sa re-init)
    const bool more = (n + 1 < 32);
    uint2 mwn;
    if (more) {
#pragma unroll
      for (int sb = 0; sb < 2; sb++)
#pragma unroll
        for (int c = 0; c < 4; c++)
          kf[sb][c] = *(const bf8*)(Kl + ((size_t)((2 * (n + 1) + sb) * 4 + c) << 9));
      mwn = *(const uint2*)(mroww + ((n + 1) << 1));
    }
    // exp2 + truncating pack of sa(n)
    unsigned int X0[8], X1[8];
#pragma unroll
    for (int m = 0; m < 8; m++) {
      X0[m] = PACK2(EXPU(sa0[2 * m]), EXPU(sa0[2 * m + 1]));
      X1[m] = PACK2(EXPU(sa1[2 * m]), EXPU(sa1[2 * m + 1]));
    }
    // lane^32 exchange -> PV A-frags pa[c]: lane holds P[t=l31][s=c*16+hi*8..+8]
    bf8 pa[4];
#pragma unroll
    for (int c = 0; c < 4; c++) {
      const int m0 = 4 * (c & 1);
      unsigned int a0, a1, a2, a3;
      if (c < 2) {
        a0 = X0[m0]; a1 = X0[m0 + 1]; a2 = X0[m0 + 2]; a3 = X0[m0 + 3];
      } else {
        a0 = X1[m0]; a1 = X1[m0 + 1]; a2 = X1[m0 + 2]; a3 = X1[m0 + 3];
      }
      pl32swap(a0, a2);  // -> dwords j=0, j=2
      pl32swap(a1, a3);  // -> dwords j=1, j=3
      u32x4 pdv;
      pdv[0] = a0; pdv[1] = a1; pdv[2] = a2; pdv[3] = a3;
      pa[c] = *(bf8*)&pdv;
    }
    // re-init sa with tile n+1's mask (sa(n) fully consumed by exp above)
    if (more) {
      const unsigned int w0 = mwn.x >> (4 * hi);
      const unsigned int w1 = mwn.y >> (4 * hi);
#pragma unroll
      for (int r = 0; r < 16; r++) {
        const int sh = (r & 3) + 8 * (r >> 2);
        sa0[r] = ((w0 >> sh) & 1u) ? -1e9f : 0.f;
        sa1[r] = ((w1 >> sh) & 1u) ? -1e9f : 0.f;
      }
    }
    // merged MFMA cluster: PV(n) and scores(n+1) — 5 independent chains
    __builtin_amdgcn_s_setprio(1);
#pragma unroll
    for (int c = 0; c < 4; c++) {
      dacc = MFMA32(pa[c], ones, dacc);
      oacc0 = MFMA32(pa[c], vf[c][0], oacc0);
      oacc1 = MFMA32(pa[c], vf[c][1], oacc1);
    }
    if (more) {
#pragma unroll
      for (int c = 0; c < 4; c++) {
        sa0 = MFMA32(kf[0][c], qf[c], sa0);
        sa1 = MFMA32(kf[1][c], qf[c], sa1);
      }
    }
    __builtin_amdgcn_s_setprio(0);
  }

  // epilogue: O row t = (r&3)+8*(r>>2)+4*hi, col d = dblk*32 + l31
#pragma unroll
  for (int r = 0; r < 16; r++) {
    const int tl = (r & 3) + 8 * (r >> 2) + 4 * hi;
    const float inv = 1.0f / dacc[r];
    const size_t off = (size_t)(b * Tt + t0 + wm + tl) * Ee + h * 64 + l31;
    O[off] = f2bf(oacc0[r] * inv);
    O[off + 32] = f2bf(oacc1[r] * inv);
  }
}

// ---------------- launcher ----------------
extern "C" void kernel_launch(void* const* d_in, const int* in_sizes, int n_in,
                              void* d_out, int out_size, void* d_ws, size_t ws_size,
                              hipStream_t stream) {
  const float* x    = (const float*)d_in[0];
  const float* ctx  = (const float*)d_in[1];
  const int*   mask = (const int*)d_in[2];
  const float* w_in = (const float*)d_in[3];
  const float* b_in = (const float*)d_in[4];
  const float* wq   = (const float*)d_in[5];
  const float* bq   = (const float*)d_in[6];
  const float* wk   = (const float*)d_in[7];
  const float* bk   = (const float*)d_in[8];
  const float* wv   = (const float*)d_in[9];
  const float* bv   = (const float*)d_in[10];
  const float* wo   = (const float*)d_in[11];
  const float* bo   = (const float*)d_in[12];

  const float qsc = 0.04419417382415922f * 1.4426950408889634f;  // E^-0.5 * log2(e)

  unsigned short* ws = (unsigned short*)d_ws;
  unsigned int*   maskp = (unsigned int*)ws;        // [4*2048*64] = 2MB
  unsigned short* wkvb  = ws + 1048576;             // [1024,512]
  unsigned short* wob   = ws + 1572864;             // [256,512]
  unsigned short* wqin  = ws + 1703936;             // [512,256]
  float*          bqinb = (float*)(ws + 1835008);   // [512]
  unsigned short* Qb    = ws + 1836032;             // [8192,512]
  unsigned short* Kfb   = ws + 6030336;             // K fragment-order [32bh][131072]
  unsigned short* Vfb   = ws + 10224640;            // V fragment-order [32bh][131072]
  unsigned short* Ob    = ws + 14418944;            // [8192,512]

  prep<<<688, 256, 0, stream>>>(w_in, b_in, wq, bq, wk, wv, wo,
                                wkvb, wob, wqin, bqinb, qsc);
  qkv<<<2816, 256, 0, stream>>>(x, ctx, wqin, bqinb, wkvb, bk, bv, Qb, Kfb, Vfb,
                                mask, maskp);
  attn<<<512, 256, 0, stream>>>(Qb, Kfb, Vfb, maskp, Ob);
  gemm_bt<false, 64, 64, 2><<<dim3(128, 4), 256, 0, stream>>>(
      Ob, wob, bo, d_out, 8192, 256, 512);
}

// Round 10
// 239.629 us; speedup vs baseline: 2.6568x; 1.0054x over previous
//
#include <hip/hip_runtime.h>
#include <cstdint>
#include <cstddef>

#define Bb 4
#define Tt 2048
#define Ssz 2048
#define Cc 256
#define Ee 512
#define Hh 8

typedef short bf8 __attribute__((ext_vector_type(8)));
typedef float f4 __attribute__((ext_vector_type(4)));
typedef float f16v __attribute__((ext_vector_type(16)));
typedef unsigned int u32x2 __attribute__((ext_vector_type(2)));
typedef unsigned int u32x4 __attribute__((ext_vector_type(4)));

__device__ __forceinline__ unsigned short f2bf(float x) {
  unsigned int u = __float_as_uint(x);
  u += 0x7fffu + ((u >> 16) & 1u);
  return (unsigned short)(u >> 16);
}

__device__ __forceinline__ bf8 cvt8(float4 a, float4 b) {
  bf8 r;
  r[0] = (short)f2bf(a.x); r[1] = (short)f2bf(a.y);
  r[2] = (short)f2bf(a.z); r[3] = (short)f2bf(a.w);
  r[4] = (short)f2bf(b.x); r[5] = (short)f2bf(b.y);
  r[6] = (short)f2bf(b.z); r[7] = (short)f2bf(b.w);
  return r;
}

// pack two f32 (bit-truncated) into one dword of 2 bf16 via v_perm_b32
#if __has_builtin(__builtin_amdgcn_perm)
#define PACK2(u0, u1) __builtin_amdgcn_perm((u1), (u0), 0x07060302u)
#else
#define PACK2(u0, u1) (((u0) >> 16) | ((u1) & 0xffff0000u))
#endif

#define EXPU(v) __float_as_uint(__builtin_amdgcn_exp2f(v))
#define MFMA32(a, b, c) __builtin_amdgcn_mfma_f32_32x32x16_bf16((a), (b), (c), 0, 0, 0)

// v_permlane32_swap_b32: a.upper32lanes <-> b.lower32lanes (dual result)
__device__ __forceinline__ void pl32swap(unsigned int& a, unsigned int& b) {
#if __has_builtin(__builtin_amdgcn_permlane32_swap)
  u32x2 r = __builtin_amdgcn_permlane32_swap(a, b, false, false);
  a = r[0];
  b = r[1];
#else
  unsigned int ax = (unsigned int)__shfl_xor((int)a, 32);
  unsigned int bx = (unsigned int)__shfl_xor((int)b, 32);
  bool hi = (threadIdx.x & 32) != 0;
  unsigned int an = hi ? bx : a;
  unsigned int bn = hi ? b : ax;
  a = an;
  b = bn;
#endif
}

// ---------------- prep: weight casts + wqin GEMM + bqin ----------------
// bid<512: wk/wv cast; <640: wo cast; <672: wqin; <688: bqin
__global__ __launch_bounds__(256) void prep(const float* __restrict__ w_in,
                                            const float* __restrict__ b_in,
                                            const float* __restrict__ wq,
                                            const float* __restrict__ bq,
                                            const float* __restrict__ wk,
                                            const float* __restrict__ wv,
                                            const float* __restrict__ wo,
                                            unsigned short* __restrict__ wkvb,
                                            unsigned short* __restrict__ wob,
                                            unsigned short* __restrict__ wqin,
                                            float* __restrict__ bqinb, float qsc) {
  __shared__ unsigned short sh[128][72];
  const int bid = blockIdx.x, tid = threadIdx.x;
  if (bid < 512) {
    int i = bid * 256 + tid;  // 0..131071
    const float* s = (i < 65536) ? wk : wv;
    int off = (i < 65536) ? i : i - 65536;
    float4 v = ((const float4*)s)[off];
    ushort4 o;
    o.x = f2bf(v.x); o.y = f2bf(v.y); o.z = f2bf(v.z); o.w = f2bf(v.w);
    ((ushort4*)wkvb)[i] = o;
  } else if (bid < 640) {
    int i = (bid - 512) * 256 + tid;  // 0..32767
    float4 v = ((const float4*)wo)[i];
    ushort4 o;
    o.x = f2bf(v.x); o.y = f2bf(v.y); o.z = f2bf(v.z); o.w = f2bf(v.w);
    ((ushort4*)wob)[i] = o;
  } else if (bid < 672) {
    // wqin[512,256] = (qsc*wq)[512,512] . w_in[512,256]
    const int idx = bid - 640;
    const int m0 = (idx & 7) * 64, n0 = (idx >> 3) * 64;
    unsigned short (*As)[72] = (unsigned short (*)[72]) & sh[0][0];
    unsigned short (*Bs)[72] = (unsigned short (*)[72]) & sh[64][0];
    const int wave = tid >> 6, lane = tid & 63;
    const int lrow = lane & 15, quad = lane >> 4;
    const int wm = (wave >> 1) * 32, wn = (wave & 1) * 32;
    const int arow = tid >> 3, ac = tid & 7;
    f4 acc[2][2];
#pragma unroll
    for (int i = 0; i < 2; i++)
#pragma unroll
      for (int j = 0; j < 2; j++) {
        f4 z = {0.f, 0.f, 0.f, 0.f};
        acc[i][j] = z;
      }
    for (int kt = 0; kt < 8; kt++) {
#pragma unroll
      for (int i = 0; i < 2; i++) {
        int row = arow + i * 32;
        const float* src = wq + (size_t)(m0 + row) * Ee + kt * 64 + ac * 8;
        float4 v0 = *(const float4*)src, v1 = *(const float4*)(src + 4);
        bf8 av;
        av[0] = (short)f2bf(v0.x * qsc); av[1] = (short)f2bf(v0.y * qsc);
        av[2] = (short)f2bf(v0.z * qsc); av[3] = (short)f2bf(v0.w * qsc);
        av[4] = (short)f2bf(v1.x * qsc); av[5] = (short)f2bf(v1.y * qsc);
        av[6] = (short)f2bf(v1.z * qsc); av[7] = (short)f2bf(v1.w * qsc);
        *(bf8*)&As[row][ac * 8] = av;
        int c = n0 + row;
        bf8 bv;
#pragma unroll
        for (int k = 0; k < 8; k++)
          bv[k] = (short)f2bf(w_in[(size_t)(kt * 64 + ac * 8 + k) * Cc + c]);
        *(bf8*)&Bs[row][ac * 8] = bv;
      }
      __syncthreads();
#pragma unroll
      for (int kk = 0; kk < 2; kk++) {
        bf8 af[2], bff[2];
#pragma unroll
        for (int i = 0; i < 2; i++) af[i] = *(const bf8*)&As[wm + i * 16 + lrow][kk * 32 + quad * 8];
#pragma unroll
        for (int j = 0; j < 2; j++) bff[j] = *(const bf8*)&Bs[wn + j * 16 + lrow][kk * 32 + quad * 8];
#pragma unroll
        for (int i = 0; i < 2; i++)
#pragma unroll
          for (int j = 0; j < 2; j++)
            acc[i][j] = __builtin_amdgcn_mfma_f32_16x16x32_bf16(af[i], bff[j], acc[i][j], 0, 0, 0);
      }
      __syncthreads();
    }
#pragma unroll
    for (int j = 0; j < 2; j++)
#pragma unroll
      for (int i = 0; i < 2; i++)
#pragma unroll
        for (int r = 0; r < 4; r++)
          wqin[(size_t)(m0 + wm + i * 16 + quad * 4 + r) * Cc + n0 + wn + j * 16 + lrow] =
              f2bf(acc[i][j][r]);
  } else {
    const int o = (bid - 672) * 32 + (tid >> 3);
    const int k0 = (tid & 7) * 64;
    float s = 0.f;
#pragma unroll
    for (int i = 0; i < 16; i++) {
      float4 w = *(const float4*)(wq + (size_t)o * Ee + k0 + i * 4);
      float4 bb = *(const float4*)(b_in + k0 + i * 4);
      s += w.x * bb.x + w.y * bb.y + w.z * bb.z + w.w * bb.w;
    }
    s += __shfl_xor(s, 1);
    s += __shfl_xor(s, 2);
    s += __shfl_xor(s, 4);
    if ((tid & 7) == 0) bqinb[o] = (s + bq[o]) * qsc;
  }
}

// ---------------- Q-GEMM + KV-GEMM + packmask, one dispatch ----------------
__global__ __launch_bounds__(256) void qkv(const float* __restrict__ x,
                                           const float* __restrict__ ctx,
                                           const unsigned short* __restrict__ wqin,
                                           const float* __restrict__ bqinb,
                                           const unsigned short* __restrict__ wkv,
                                           const float* __restrict__ bk,
                                           const float* __restrict__ bv,
                                           unsigned short* __restrict__ Qb,
                                           unsigned short* __restrict__ Kb,
                                           unsigned short* __restrict__ Vt,
                                           const int* __restrict__ mask,
                                           unsigned int* __restrict__ mp) {
  __shared__ unsigned short As[128][72];
  __shared__ unsigned short Bs[128][72];
  const int bid = blockIdx.x, tid = threadIdx.x;
  if (bid >= 768) {
    int i = (bid - 768) * 256 + tid;  // 0..524287
    const int4* src = (const int4*)mask + (size_t)i * 8;
    unsigned int w = 0;
#pragma unroll
    for (int k = 0; k < 8; k++) {
      int4 v = src[k];
      w |= (unsigned int)(v.x != 0) << (k * 4);
      w |= (unsigned int)(v.y != 0) << (k * 4 + 1);
      w |= (unsigned int)(v.z != 0) << (k * 4 + 2);
      w |= (unsigned int)(v.w != 0) << (k * 4 + 3);
    }
    mp[i] = w;
    return;
  }
  const bool isQ = bid < 256;
  const int idx = isQ ? bid : bid - 256;
  const int m0 = (idx & 63) * 128;
  const int n0 = (idx >> 6) * 128;
  const int K = isQ ? 256 : 512;
  const float* A = isQ ? x : ctx;
  const unsigned short* Bt = isQ ? wqin : wkv;

  const int wave = tid >> 6, lane = tid & 63;
  const int lrow = lane & 15, quad = lane >> 4;
  const int wm = (wave >> 1) * 64, wn = (wave & 1) * 64;
  const int arow = tid >> 3, ac = tid & 7;

  f4 acc[4][4];
#pragma unroll
  for (int i = 0; i < 4; i++)
#pragma unroll
    for (int j = 0; j < 4; j++) {
      f4 z = {0.f, 0.f, 0.f, 0.f};
      acc[i][j] = z;
    }

  float4 ap0[4], ap1[4];
  bf8 bpre[4];
#pragma unroll
  for (int i = 0; i < 4; i++) {
    const float* src = A + (size_t)(m0 + arow + i * 32) * K + ac * 8;
    ap0[i] = *(const float4*)src;
    ap1[i] = *(const float4*)(src + 4);
    bpre[i] = *(const bf8*)(Bt + (size_t)(n0 + arow + i * 32) * K + ac * 8);
  }

  const int nkt = K >> 6;
  for (int kt = 0; kt < nkt; ++kt) {
#pragma unroll
    for (int i = 0; i < 4; i++) {
      *(bf8*)&As[arow + i * 32][ac * 8] = cvt8(ap0[i], ap1[i]);
      *(bf8*)&Bs[arow + i * 32][ac * 8] = bpre[i];
    }
    __syncthreads();
    if (kt + 1 < nkt) {
      int k0 = (kt + 1) << 6;
#pragma unroll
      for (int i = 0; i < 4; i++) {
        const float* src = A + (size_t)(m0 + arow + i * 32) * K + k0 + ac * 8;
        ap0[i] = *(const float4*)src;
        ap1[i] = *(const float4*)(src + 4);
        bpre[i] = *(const bf8*)(Bt + (size_t)(n0 + arow + i * 32) * K + k0 + ac * 8);
      }
    }
#pragma unroll
    for (int kk = 0; kk < 2; kk++) {
      bf8 af[4], bff[4];
#pragma unroll
      for (int i = 0; i < 4; i++)
        af[i] = *(const bf8*)&As[wm + i * 16 + lrow][kk * 32 + quad * 8];
#pragma unroll
      for (int j = 0; j < 4; j++)
        bff[j] = *(const bf8*)&Bs[wn + j * 16 + lrow][kk * 32 + quad * 8];
#pragma unroll
      for (int i = 0; i < 4; i++)
#pragma unroll
        for (int j = 0; j < 4; j++)
          acc[i][j] = __builtin_amdgcn_mfma_f32_16x16x32_bf16(af[i], bff[j],
                                                              acc[i][j], 0, 0, 0);
    }
    __syncthreads();
  }

  if (isQ) {
#pragma unroll
    for (int j = 0; j < 4; j++) {
      int col = n0 + wn + j * 16 + lrow;
      float bvv = bqinb[col];
#pragma unroll
      for (int i = 0; i < 4; i++)
#pragma unroll
        for (int r = 0; r < 4; r++)
          Qb[(size_t)(m0 + wm + i * 16 + quad * 4 + r) * Ee + col] =
              f2bf(acc[i][j][r] + bvv);
    }
  } else if (n0 < 512) {  // K half (uniform per block)
#pragma unroll
    for (int j = 0; j < 4; j++) {
      int col = n0 + wn + j * 16 + lrow;
      float bvv = bk[col];
#pragma unroll
      for (int i = 0; i < 4; i++)
#pragma unroll
        for (int r = 0; r < 4; r++)
          Kb[(size_t)(m0 + wm + i * 16 + quad * 4 + r) * Ee + col] =
              f2bf(acc[i][j][r] + bvv);
    }
  } else {  // V half -> transposed store
#pragma unroll
    for (int j = 0; j < 4; j++) {
      int d = n0 - 512 + wn + j * 16 + lrow;
      int h = d >> 6, dd = d & 63;
      float bvv = bv[d];
#pragma unroll
      for (int i = 0; i < 4; i++) {
        int tok = m0 + wm + i * 16 + quad * 4;  // 4 consecutive tokens
        int b = tok >> 11, sl = tok & 2047;
        ushort4 pk;
        pk.x = f2bf(acc[i][j][0] + bvv);
        pk.y = f2bf(acc[i][j][1] + bvv);
        pk.z = f2bf(acc[i][j][2] + bvv);
        pk.w = f2bf(acc[i][j][3] + bvv);
        *(ushort4*)(Vt + (size_t)((b * Hh + h) * 64 + dd) * Ssz + sl) = pk;
      }
    }
  }
}

// ---------------- GEMM: C[M,N] = A[M,K]*Bt[N,K]^T + bias (bf16 A) ----------------
template <bool OUT_BF16, int BM, int BN, int WGM>
__global__ __launch_bounds__(256) void gemm_bt(const unsigned short* __restrict__ A,
                                               const unsigned short* __restrict__ Bt,
                                               const float* __restrict__ bias0,
                                               void* __restrict__ Cout,
                                               int M, int N, int K) {
  constexpr int WGN = 4 / WGM;
  constexpr int MI = BM / (WGM * 16);
  constexpr int NJ = BN / (WGN * 16);
  constexpr int NA = BM / 32;
  constexpr int NB = BN / 32;
  __shared__ unsigned short As[BM][72];
  __shared__ unsigned short Bs[BN][72];
  const int tid = threadIdx.x;
  const int wave = tid >> 6, lane = tid & 63;
  const int lrow = lane & 15, quad = lane >> 4;
  const int wm = (wave / WGN) * (BM / WGM);
  const int wn = (wave % WGN) * (BN / WGN);
  const int m0 = blockIdx.x * BM, n0 = blockIdx.y * BN;
  const int arow = tid >> 3, ac = tid & 7;

  f4 acc[MI][NJ];
#pragma unroll
  for (int i = 0; i < MI; i++)
#pragma unroll
    for (int j = 0; j < NJ; j++) {
      f4 z = {0.f, 0.f, 0.f, 0.f};
      acc[i][j] = z;
    }

  bf8 apre[NA], bpre[NB];
#pragma unroll
  for (int i = 0; i < NA; i++)
    apre[i] = *(const bf8*)(A + (size_t)(m0 + arow + i * 32) * K + ac * 8);
#pragma unroll
  for (int i = 0; i < NB; i++)
    bpre[i] = *(const bf8*)(Bt + (size_t)(n0 + arow + i * 32) * K + ac * 8);

  const int nkt = K >> 6;
  for (int kt = 0; kt < nkt; ++kt) {
#pragma unroll
    for (int i = 0; i < NA; i++) *(bf8*)&As[arow + i * 32][ac * 8] = apre[i];
#pragma unroll
    for (int i = 0; i < NB; i++) *(bf8*)&Bs[arow + i * 32][ac * 8] = bpre[i];
    __syncthreads();
    if (kt + 1 < nkt) {
      int k0 = (kt + 1) << 6;
#pragma unroll
      for (int i = 0; i < NA; i++)
        apre[i] = *(const bf8*)(A + (size_t)(m0 + arow + i * 32) * K + k0 + ac * 8);
#pragma unroll
      for (int i = 0; i < NB; i++)
        bpre[i] = *(const bf8*)(Bt + (size_t)(n0 + arow + i * 32) * K + k0 + ac * 8);
    }
#pragma unroll
    for (int kk = 0; kk < 2; kk++) {
      bf8 af[MI], bff[NJ];
#pragma unroll
      for (int i = 0; i < MI; i++)
        af[i] = *(const bf8*)&As[wm + i * 16 + lrow][kk * 32 + quad * 8];
#pragma unroll
      for (int j = 0; j < NJ; j++)
        bff[j] = *(const bf8*)&Bs[wn + j * 16 + lrow][kk * 32 + quad * 8];
#pragma unroll
      for (int i = 0; i < MI; i++)
#pragma unroll
        for (int j = 0; j < NJ; j++)
          acc[i][j] = __builtin_amdgcn_mfma_f32_16x16x32_bf16(af[i], bff[j],
                                                              acc[i][j], 0, 0, 0);
    }
    __syncthreads();
  }

#pragma unroll
  for (int j = 0; j < NJ; j++) {
    int col = n0 + wn + j * 16 + lrow;
    float bvv = bias0 ? bias0[col] : 0.f;
#pragma unroll
    for (int i = 0; i < MI; i++) {
#pragma unroll
      for (int r = 0; r < 4; r++) {
        int row = m0 + wm + i * 16 + quad * 4 + r;
        float v = acc[i][j][r] + bvv;
        if (OUT_BF16)
          ((unsigned short*)Cout)[(size_t)row * N + col] = f2bf(v);
        else
          ((float*)Cout)[(size_t)row * N + col] = v;
      }
    }
  }
}

// ------- fused masked cross-attention (R3 body, in-block split-S, 4 waves/SIMD) ----
// 8-round model: R3's LDS-staged body (59.5us) is latency-bound with no pipe
// >43%; the only untried lever left is 4 waves/SIMD, which failed in R5 (3.7x
// HBM traffic from partial-O + cross-block L2 thrash) and R7 (launch_bounds
// reg-cap 64 -> GB-scale spills). This version gets 4 waves/SIMD with BYTE-
// IDENTICAL traffic and no reg cap: 512-thread blocks; waves 0-3 take
// s<1024, waves 4-7 s>=1024 for the SAME 128 t; each group has its own
// double-buffered LDS K/V (73.7KB/block -> 2 blocks/CU -> 16 waves/CU).
// Grid/bh mapping/per-CU read volume identical to R3. Partials merge in-block
// through LDS f32 (aliasing the staging memory after the final barrier, R7's
// proven merge). launch_bounds(512,2) -> >=128 VGPR/wave; R3 body used 68.
__global__ __launch_bounds__(512, 2) void attn(const unsigned short* __restrict__ Q,
                                               const unsigned short* __restrict__ K,
                                               const unsigned short* __restrict__ Vt,
                                               const unsigned int* __restrict__ mp,
                                               unsigned short* __restrict__ O) {
  __shared__ __align__(16) unsigned char smem[73728];
  const int tid = threadIdx.x;
  const int wave = tid >> 6, lane = tid & 63;
  const int l31 = lane & 31, hi = lane >> 5;
  const int wsub = wave & 3, grp = wave >> 2;  // grp = s-half
  const int bid = blockIdx.x;
  const int bh = bid & 31, b = bh >> 3, h = bh & 7;
  const int t0 = (bid >> 5) * 128;
  const int tw = t0 + wsub * 32;
  const int sbase = grp << 10;
  const int gtid = tid & 255;                  // id within the 4-wave group
  const int arow = gtid >> 3, ac = gtid & 7;

  typedef unsigned short tile2_t[2][64][72];   // [buf][row][col], 18432 B
  tile2_t& Ks = *(tile2_t*)(smem + grp * 36864);
  tile2_t& Vts = *(tile2_t*)(smem + grp * 36864 + 18432);

  // Q B-frags: lane (t=l31, hi) holds Q[t][c*16 + hi*8 .. +8]
  const unsigned short* Qrow =
      Q + (size_t)(b * Tt + tw + l31) * Ee + h * 64 + hi * 8;
  bf8 qf[4];
#pragma unroll
  for (int c = 0; c < 4; c++) qf[c] = *(const bf8*)(Qrow + c * 16);

  f16v oacc0, oacc1, dacc;
#pragma unroll
  for (int r = 0; r < 16; r++) {
    oacc0[r] = 0.f;
    oacc1[r] = 0.f;
    dacc[r] = 0.f;
  }
  bf8 ones;
#pragma unroll
  for (int k = 0; k < 8; k++) ones[k] = (short)0x3F80;  // bf16 1.0

  const unsigned short* Kbase = K + ((size_t)b * Ssz + sbase) * Ee + h * 64;
  const unsigned short* Vbase = Vt + (size_t)((b * Hh + h) * 64) * Ssz + sbase;
  const unsigned int* mroww =
      mp + (size_t)(b * Tt + tw + l31) * 64 + (sbase >> 5);

  // prologue: stage tile 0 of this group's s-half
  bf8 kreg[2], vreg[2];
#pragma unroll
  for (int i = 0; i < 2; i++) {
    int row = arow + i * 32;
    kreg[i] = *(const bf8*)(Kbase + (size_t)row * Ee + ac * 8);
    vreg[i] = *(const bf8*)(Vbase + (size_t)row * Ssz + ac * 8);
  }
#pragma unroll
  for (int i = 0; i < 2; i++) {
    int row = arow + i * 32;
    *(bf8*)&Ks[0][row][ac * 8] = kreg[i];
    *(bf8*)&Vts[0][row][ac * 8] = vreg[i];
  }
  __syncthreads();

  for (int n = 0; n < 16; n++) {
    const int s0 = n * 64;  // local to this s-half
    const int cur = n & 1;
    // issue next-tile global loads first; latency hides under this iter's compute
    if (n + 1 < 16) {
#pragma unroll
      for (int i = 0; i < 2; i++) {
        int row = arow + i * 32;
        kreg[i] = *(const bf8*)(Kbase + (size_t)(s0 + 64 + row) * Ee + ac * 8);
        vreg[i] = *(const bf8*)(Vbase + (size_t)row * Ssz + s0 + 64 + ac * 8);
      }
    }
    const uint2 mw = *(const uint2*)(mroww + (s0 >> 5));
    const unsigned int wsh0 = mw.x >> (4 * hi);
    const unsigned int wsh1 = mw.y >> (4 * hi);

    // mask pre-init: sa row s=(r&3)+8*(r>>2)+4*hi (+32 for sa1), col t=l31
    f16v sa0, sa1;
#pragma unroll
    for (int r = 0; r < 16; r++) {
      const int shft = (r & 3) + 8 * (r >> 2);
      sa0[r] = ((wsh0 >> shft) & 1u) ? -1e9f : 0.f;
      sa1[r] = ((wsh1 >> shft) & 1u) ? -1e9f : 0.f;
    }
    // scores: S^T = K . Q^T  (two 32s x 32t blocks, k=d in 4 chunks of 16)
#pragma unroll
    for (int c = 0; c < 4; c++) {
      bf8 kf0 = *(const bf8*)&Ks[cur][l31][c * 16 + hi * 8];
      bf8 kf1 = *(const bf8*)&Ks[cur][32 + l31][c * 16 + hi * 8];
      sa0 = MFMA32(kf0, qf[c], sa0);
      sa1 = MFMA32(kf1, qf[c], sa1);
    }
    // exp2 + pack pairs (truncating bf16): X[b][m] = P[t][s=32b+2m], P[t][32b+2m+1]
    unsigned int X0[8], X1[8];
#pragma unroll
    for (int m = 0; m < 8; m++) {
      X0[m] = PACK2(EXPU(sa0[2 * m]), EXPU(sa0[2 * m + 1]));
      X1[m] = PACK2(EXPU(sa1[2 * m]), EXPU(sa1[2 * m + 1]));
    }
    // lane^32 exchange -> PV A-frags pa[c]: lane holds P[t=l31][s=c*16+hi*8..+8]
#pragma unroll
    for (int c = 0; c < 4; c++) {
      const int m0 = 4 * (c & 1);
      unsigned int a0, a1, a2, a3;
      if (c < 2) {
        a0 = X0[m0]; a1 = X0[m0 + 1]; a2 = X0[m0 + 2]; a3 = X0[m0 + 3];
      } else {
        a0 = X1[m0]; a1 = X1[m0 + 1]; a2 = X1[m0 + 2]; a3 = X1[m0 + 3];
      }
      pl32swap(a0, a2);  // -> dwords j=0, j=2
      pl32swap(a1, a3);  // -> dwords j=1, j=3
      u32x4 pdv;
      pdv[0] = a0; pdv[1] = a1; pdv[2] = a2; pdv[3] = a3;
      bf8 pa = *(bf8*)&pdv;
      bf8 vf0 = *(const bf8*)&Vts[cur][l31][c * 16 + hi * 8];
      bf8 vf1 = *(const bf8*)&Vts[cur][32 + l31][c * 16 + hi * 8];
      dacc = MFMA32(pa, ones, dacc);
      oacc0 = MFMA32(pa, vf0, oacc0);
      oacc1 = MFMA32(pa, vf1, oacc1);
    }
    // stage next tile into the alternate buffer (others still read cur)
    if (n + 1 < 16) {
#pragma unroll
      for (int i = 0; i < 2; i++) {
        int row = arow + i * 32;
        *(bf8*)&Ks[cur ^ 1][row][ac * 8] = kreg[i];
        *(bf8*)&Vts[cur ^ 1][row][ac * 8] = vreg[i];
      }
    }
    __syncthreads();
  }

  // in-block merge: group 1 publishes f32 partials (aliasing the staging LDS,
  // safe after the final loop barrier); group 0 merges + stores once.
  float (*mbuf)[64][48] = (float (*)[64][48])smem;  // [wsub][lane][o0 16|o1 16|d 16]
  if (grp) {
#pragma unroll
    for (int q = 0; q < 4; q++) {
      float4 v0 = {oacc0[4 * q], oacc0[4 * q + 1], oacc0[4 * q + 2], oacc0[4 * q + 3]};
      float4 v1 = {oacc1[4 * q], oacc1[4 * q + 1], oacc1[4 * q + 2], oacc1[4 * q + 3]};
      float4 v2 = {dacc[4 * q], dacc[4 * q + 1], dacc[4 * q + 2], dacc[4 * q + 3]};
      *(float4*)&mbuf[wsub][lane][4 * q] = v0;
      *(float4*)&mbuf[wsub][lane][16 + 4 * q] = v1;
      *(float4*)&mbuf[wsub][lane][32 + 4 * q] = v2;
    }
  }
  __syncthreads();
  if (!grp) {
    // epilogue: O row t = (r&3)+8*(r>>2)+4*hi, col d = dblk*32 + l31
#pragma unroll
    for (int r = 0; r < 16; r++) {
      const int tl = (r & 3) + 8 * (r >> 2) + 4 * hi;
      const float inv = 1.0f / (dacc[r] + mbuf[wsub][lane][32 + r]);
      const size_t off = (size_t)(b * Tt + tw + tl) * Ee + h * 64 + l31;
      O[off] = f2bf((oacc0[r] + mbuf[wsub][lane][r]) * inv);
      O[off + 32] = f2bf((oacc1[r] + mbuf[wsub][lane][16 + r]) * inv);
    }
  }
}

// ---------------- launcher ----------------
extern "C" void kernel_launch(void* const* d_in, const int* in_sizes, int n_in,
                              void* d_out, int out_size, void* d_ws, size_t ws_size,
                              hipStream_t stream) {
  const float* x    = (const float*)d_in[0];
  const float* ctx  = (const float*)d_in[1];
  const int*   mask = (const int*)d_in[2];
  const float* w_in = (const float*)d_in[3];
  const float* b_in = (const float*)d_in[4];
  const float* wq   = (const float*)d_in[5];
  const float* bq   = (const float*)d_in[6];
  const float* wk   = (const float*)d_in[7];
  const float* bk   = (const float*)d_in[8];
  const float* wv   = (const float*)d_in[9];
  const float* bv   = (const float*)d_in[10];
  const float* wo   = (const float*)d_in[11];
  const float* bo   = (const float*)d_in[12];

  const float qsc = 0.04419417382415922f * 1.4426950408889634f;  // E^-0.5 * log2(e)

  unsigned short* ws = (unsigned short*)d_ws;
  unsigned int*   maskp = (unsigned int*)ws;        // [4*2048*64] = 2MB
  unsigned short* wkvb  = ws + 1048576;             // [1024,512]
  unsigned short* wob   = ws + 1572864;             // [256,512]
  unsigned short* wqin  = ws + 1703936;             // [512,256]
  float*          bqinb = (float*)(ws + 1835008);   // [512]
  unsigned short* Qb    = ws + 1836032;             // [8192,512]
  unsigned short* Kb    = ws + 6030336;             // [8192,512]
  unsigned short* Vtb   = ws + 10224640;            // [32,64,2048]
  unsigned short* Ob    = ws + 14418944;            // [8192,512]

  prep<<<688, 256, 0, stream>>>(w_in, b_in, wq, bq, wk, wv, wo,
                                wkvb, wob, wqin, bqinb, qsc);
  qkv<<<2816, 256, 0, stream>>>(x, ctx, wqin, bqinb, wkvb, bk, bv, Qb, Kb, Vtb,
                                mask, maskp);
  attn<<<512, 512, 0, stream>>>(Qb, Kb, Vtb, maskp, Ob);
  gemm_bt<false, 64, 64, 2><<<dim3(128, 4), 256, 0, stream>>>(
      Ob, wob, bo, d_out, 8192, 256, 512);
}

// Round 11
// 230.023 us; speedup vs baseline: 2.7677x; 1.0418x over previous
//
#include <hip/hip_runtime.h>
#include <cstdint>
#include <cstddef>

#define Bb 4
#define Tt 2048
#define Ssz 2048
#define Cc 256
#define Ee 512
#define Hh 8

typedef short bf8 __attribute__((ext_vector_type(8)));
typedef float f4 __attribute__((ext_vector_type(4)));
typedef float f16v __attribute__((ext_vector_type(16)));
typedef unsigned int u32x2 __attribute__((ext_vector_type(2)));
typedef unsigned int u32x4 __attribute__((ext_vector_type(4)));

__device__ __forceinline__ unsigned short f2bf(float x) {
  unsigned int u = __float_as_uint(x);
  u += 0x7fffu + ((u >> 16) & 1u);
  return (unsigned short)(u >> 16);
}

__device__ __forceinline__ bf8 cvt8(float4 a, float4 b) {
  bf8 r;
  r[0] = (short)f2bf(a.x); r[1] = (short)f2bf(a.y);
  r[2] = (short)f2bf(a.z); r[3] = (short)f2bf(a.w);
  r[4] = (short)f2bf(b.x); r[5] = (short)f2bf(b.y);
  r[6] = (short)f2bf(b.z); r[7] = (short)f2bf(b.w);
  return r;
}

// pack two f32 (bit-truncated) into one dword of 2 bf16 via v_perm_b32
#if __has_builtin(__builtin_amdgcn_perm)
#define PACK2(u0, u1) __builtin_amdgcn_perm((u1), (u0), 0x07060302u)
#else
#define PACK2(u0, u1) (((u0) >> 16) | ((u1) & 0xffff0000u))
#endif

#define EXPU(v) __float_as_uint(__builtin_amdgcn_exp2f(v))
#define MFMA32(a, b, c) __builtin_amdgcn_mfma_f32_32x32x16_bf16((a), (b), (c), 0, 0, 0)

// v_permlane32_swap_b32: a.upper32lanes <-> b.lower32lanes (dual result)
__device__ __forceinline__ void pl32swap(unsigned int& a, unsigned int& b) {
#if __has_builtin(__builtin_amdgcn_permlane32_swap)
  u32x2 r = __builtin_amdgcn_permlane32_swap(a, b, false, false);
  a = r[0];
  b = r[1];
#else
  unsigned int ax = (unsigned int)__shfl_xor((int)a, 32);
  unsigned int bx = (unsigned int)__shfl_xor((int)b, 32);
  bool hi = (threadIdx.x & 32) != 0;
  unsigned int an = hi ? bx : a;
  unsigned int bn = hi ? b : ax;
  a = an;
  b = bn;
#endif
}

// ---------------- prep: weight casts + wqin GEMM + bqin ----------------
// bid<512: wk/wv cast; <640: wo cast; <672: wqin; <688: bqin
__global__ __launch_bounds__(256) void prep(const float* __restrict__ w_in,
                                            const float* __restrict__ b_in,
                                            const float* __restrict__ wq,
                                            const float* __restrict__ bq,
                                            const float* __restrict__ wk,
                                            const float* __restrict__ wv,
                                            const float* __restrict__ wo,
                                            unsigned short* __restrict__ wkvb,
                                            unsigned short* __restrict__ wob,
                                            unsigned short* __restrict__ wqin,
                                            float* __restrict__ bqinb, float qsc) {
  __shared__ unsigned short sh[128][72];
  const int bid = blockIdx.x, tid = threadIdx.x;
  if (bid < 512) {
    int i = bid * 256 + tid;  // 0..131071
    const float* s = (i < 65536) ? wk : wv;
    int off = (i < 65536) ? i : i - 65536;
    float4 v = ((const float4*)s)[off];
    ushort4 o;
    o.x = f2bf(v.x); o.y = f2bf(v.y); o.z = f2bf(v.z); o.w = f2bf(v.w);
    ((ushort4*)wkvb)[i] = o;
  } else if (bid < 640) {
    int i = (bid - 512) * 256 + tid;  // 0..32767
    float4 v = ((const float4*)wo)[i];
    ushort4 o;
    o.x = f2bf(v.x); o.y = f2bf(v.y); o.z = f2bf(v.z); o.w = f2bf(v.w);
    ((ushort4*)wob)[i] = o;
  } else if (bid < 672) {
    // wqin[512,256] = (qsc*wq)[512,512] . w_in[512,256]
    const int idx = bid - 640;
    const int m0 = (idx & 7) * 64, n0 = (idx >> 3) * 64;
    unsigned short (*As)[72] = (unsigned short (*)[72]) & sh[0][0];
    unsigned short (*Bs)[72] = (unsigned short (*)[72]) & sh[64][0];
    const int wave = tid >> 6, lane = tid & 63;
    const int lrow = lane & 15, quad = lane >> 4;
    const int wm = (wave >> 1) * 32, wn = (wave & 1) * 32;
    const int arow = tid >> 3, ac = tid & 7;
    f4 acc[2][2];
#pragma unroll
    for (int i = 0; i < 2; i++)
#pragma unroll
      for (int j = 0; j < 2; j++) {
        f4 z = {0.f, 0.f, 0.f, 0.f};
        acc[i][j] = z;
      }
    for (int kt = 0; kt < 8; kt++) {
#pragma unroll
      for (int i = 0; i < 2; i++) {
        int row = arow + i * 32;
        const float* src = wq + (size_t)(m0 + row) * Ee + kt * 64 + ac * 8;
        float4 v0 = *(const float4*)src, v1 = *(const float4*)(src + 4);
        bf8 av;
        av[0] = (short)f2bf(v0.x * qsc); av[1] = (short)f2bf(v0.y * qsc);
        av[2] = (short)f2bf(v0.z * qsc); av[3] = (short)f2bf(v0.w * qsc);
        av[4] = (short)f2bf(v1.x * qsc); av[5] = (short)f2bf(v1.y * qsc);
        av[6] = (short)f2bf(v1.z * qsc); av[7] = (short)f2bf(v1.w * qsc);
        *(bf8*)&As[row][ac * 8] = av;
        int c = n0 + row;
        bf8 bv;
#pragma unroll
        for (int k = 0; k < 8; k++)
          bv[k] = (short)f2bf(w_in[(size_t)(kt * 64 + ac * 8 + k) * Cc + c]);
        *(bf8*)&Bs[row][ac * 8] = bv;
      }
      __syncthreads();
#pragma unroll
      for (int kk = 0; kk < 2; kk++) {
        bf8 af[2], bff[2];
#pragma unroll
        for (int i = 0; i < 2; i++) af[i] = *(const bf8*)&As[wm + i * 16 + lrow][kk * 32 + quad * 8];
#pragma unroll
        for (int j = 0; j < 2; j++) bff[j] = *(const bf8*)&Bs[wn + j * 16 + lrow][kk * 32 + quad * 8];
#pragma unroll
        for (int i = 0; i < 2; i++)
#pragma unroll
          for (int j = 0; j < 2; j++)
            acc[i][j] = __builtin_amdgcn_mfma_f32_16x16x32_bf16(af[i], bff[j], acc[i][j], 0, 0, 0);
      }
      __syncthreads();
    }
#pragma unroll
    for (int j = 0; j < 2; j++)
#pragma unroll
      for (int i = 0; i < 2; i++)
#pragma unroll
        for (int r = 0; r < 4; r++)
          wqin[(size_t)(m0 + wm + i * 16 + quad * 4 + r) * Cc + n0 + wn + j * 16 + lrow] =
              f2bf(acc[i][j][r]);
  } else {
    const int o = (bid - 672) * 32 + (tid >> 3);
    const int k0 = (tid & 7) * 64;
    float s = 0.f;
#pragma unroll
    for (int i = 0; i < 16; i++) {
      float4 w = *(const float4*)(wq + (size_t)o * Ee + k0 + i * 4);
      float4 bb = *(const float4*)(b_in + k0 + i * 4);
      s += w.x * bb.x + w.y * bb.y + w.z * bb.z + w.w * bb.w;
    }
    s += __shfl_xor(s, 1);
    s += __shfl_xor(s, 2);
    s += __shfl_xor(s, 4);
    if ((tid & 7) == 0) bqinb[o] = (s + bq[o]) * qsc;
  }
}

// ---------------- Q-GEMM + KV-GEMM + packmask, one dispatch ----------------
__global__ __launch_bounds__(256) void qkv(const float* __restrict__ x,
                                           const float* __restrict__ ctx,
                                           const unsigned short* __restrict__ wqin,
                                           const float* __restrict__ bqinb,
                                           const unsigned short* __restrict__ wkv,
                                           const float* __restrict__ bk,
                                           const float* __restrict__ bv,
                                           unsigned short* __restrict__ Qb,
                                           unsigned short* __restrict__ Kb,
                                           unsigned short* __restrict__ Vt,
                                           const int* __restrict__ mask,
                                           unsigned int* __restrict__ mp) {
  __shared__ unsigned short As[128][72];
  __shared__ unsigned short Bs[128][72];
  const int bid = blockIdx.x, tid = threadIdx.x;
  if (bid >= 768) {
    int i = (bid - 768) * 256 + tid;  // 0..524287
    const int4* src = (const int4*)mask + (size_t)i * 8;
    unsigned int w = 0;
#pragma unroll
    for (int k = 0; k < 8; k++) {
      int4 v = src[k];
      w |= (unsigned int)(v.x != 0) << (k * 4);
      w |= (unsigned int)(v.y != 0) << (k * 4 + 1);
      w |= (unsigned int)(v.z != 0) << (k * 4 + 2);
      w |= (unsigned int)(v.w != 0) << (k * 4 + 3);
    }
    mp[i] = w;
    return;
  }
  const bool isQ = bid < 256;
  const int idx = isQ ? bid : bid - 256;
  const int m0 = (idx & 63) * 128;
  const int n0 = (idx >> 6) * 128;
  const int K = isQ ? 256 : 512;
  const float* A = isQ ? x : ctx;
  const unsigned short* Bt = isQ ? wqin : wkv;

  const int wave = tid >> 6, lane = tid & 63;
  const int lrow = lane & 15, quad = lane >> 4;
  const int wm = (wave >> 1) * 64, wn = (wave & 1) * 64;
  const int arow = tid >> 3, ac = tid & 7;

  f4 acc[4][4];
#pragma unroll
  for (int i = 0; i < 4; i++)
#pragma unroll
    for (int j = 0; j < 4; j++) {
      f4 z = {0.f, 0.f, 0.f, 0.f};
      acc[i][j] = z;
    }

  float4 ap0[4], ap1[4];
  bf8 bpre[4];
#pragma unroll
  for (int i = 0; i < 4; i++) {
    const float* src = A + (size_t)(m0 + arow + i * 32) * K + ac * 8;
    ap0[i] = *(const float4*)src;
    ap1[i] = *(const float4*)(src + 4);
    bpre[i] = *(const bf8*)(Bt + (size_t)(n0 + arow + i * 32) * K + ac * 8);
  }

  const int nkt = K >> 6;
  for (int kt = 0; kt < nkt; ++kt) {
#pragma unroll
    for (int i = 0; i < 4; i++) {
      *(bf8*)&As[arow + i * 32][ac * 8] = cvt8(ap0[i], ap1[i]);
      *(bf8*)&Bs[arow + i * 32][ac * 8] = bpre[i];
    }
    __syncthreads();
    if (kt + 1 < nkt) {
      int k0 = (kt + 1) << 6;
#pragma unroll
      for (int i = 0; i < 4; i++) {
        const float* src = A + (size_t)(m0 + arow + i * 32) * K + k0 + ac * 8;
        ap0[i] = *(const float4*)src;
        ap1[i] = *(const float4*)(src + 4);
        bpre[i] = *(const bf8*)(Bt + (size_t)(n0 + arow + i * 32) * K + k0 + ac * 8);
      }
    }
#pragma unroll
    for (int kk = 0; kk < 2; kk++) {
      bf8 af[4], bff[4];
#pragma unroll
      for (int i = 0; i < 4; i++)
        af[i] = *(const bf8*)&As[wm + i * 16 + lrow][kk * 32 + quad * 8];
#pragma unroll
      for (int j = 0; j < 4; j++)
        bff[j] = *(const bf8*)&Bs[wn + j * 16 + lrow][kk * 32 + quad * 8];
#pragma unroll
      for (int i = 0; i < 4; i++)
#pragma unroll
        for (int j = 0; j < 4; j++)
          acc[i][j] = __builtin_amdgcn_mfma_f32_16x16x32_bf16(af[i], bff[j],
                                                              acc[i][j], 0, 0, 0);
    }
    __syncthreads();
  }

  if (isQ) {
#pragma unroll
    for (int j = 0; j < 4; j++) {
      int col = n0 + wn + j * 16 + lrow;
      float bvv = bqinb[col];
#pragma unroll
      for (int i = 0; i < 4; i++)
#pragma unroll
        for (int r = 0; r < 4; r++)
          Qb[(size_t)(m0 + wm + i * 16 + quad * 4 + r) * Ee + col] =
              f2bf(acc[i][j][r] + bvv);
    }
  } else if (n0 < 512) {  // K half (uniform per block)
#pragma unroll
    for (int j = 0; j < 4; j++) {
      int col = n0 + wn + j * 16 + lrow;
      float bvv = bk[col];
#pragma unroll
      for (int i = 0; i < 4; i++)
#pragma unroll
        for (int r = 0; r < 4; r++)
          Kb[(size_t)(m0 + wm + i * 16 + quad * 4 + r) * Ee + col] =
              f2bf(acc[i][j][r] + bvv);
    }
  } else {  // V half -> transposed store
#pragma unroll
    for (int j = 0; j < 4; j++) {
      int d = n0 - 512 + wn + j * 16 + lrow;
      int h = d >> 6, dd = d & 63;
      float bvv = bv[d];
#pragma unroll
      for (int i = 0; i < 4; i++) {
        int tok = m0 + wm + i * 16 + quad * 4;  // 4 consecutive tokens
        int b = tok >> 11, sl = tok & 2047;
        ushort4 pk;
        pk.x = f2bf(acc[i][j][0] + bvv);
        pk.y = f2bf(acc[i][j][1] + bvv);
        pk.z = f2bf(acc[i][j][2] + bvv);
        pk.w = f2bf(acc[i][j][3] + bvv);
        *(ushort4*)(Vt + (size_t)((b * Hh + h) * 64 + dd) * Ssz + sl) = pk;
      }
    }
  }
}

// ---------------- GEMM: C[M,N] = A[M,K]*Bt[N,K]^T + bias (bf16 A) ----------------
template <bool OUT_BF16, int BM, int BN, int WGM>
__global__ __launch_bounds__(256) void gemm_bt(const unsigned short* __restrict__ A,
                                               const unsigned short* __restrict__ Bt,
                                               const float* __restrict__ bias0,
                                               void* __restrict__ Cout,
                                               int M, int N, int K) {
  constexpr int WGN = 4 / WGM;
  constexpr int MI = BM / (WGM * 16);
  constexpr int NJ = BN / (WGN * 16);
  constexpr int NA = BM / 32;
  constexpr int NB = BN / 32;
  __shared__ unsigned short As[BM][72];
  __shared__ unsigned short Bs[BN][72];
  const int tid = threadIdx.x;
  const int wave = tid >> 6, lane = tid & 63;
  const int lrow = lane & 15, quad = lane >> 4;
  const int wm = (wave / WGN) * (BM / WGM);
  const int wn = (wave % WGN) * (BN / WGN);
  const int m0 = blockIdx.x * BM, n0 = blockIdx.y * BN;
  const int arow = tid >> 3, ac = tid & 7;

  f4 acc[MI][NJ];
#pragma unroll
  for (int i = 0; i < MI; i++)
#pragma unroll
    for (int j = 0; j < NJ; j++) {
      f4 z = {0.f, 0.f, 0.f, 0.f};
      acc[i][j] = z;
    }

  bf8 apre[NA], bpre[NB];
#pragma unroll
  for (int i = 0; i < NA; i++)
    apre[i] = *(const bf8*)(A + (size_t)(m0 + arow + i * 32) * K + ac * 8);
#pragma unroll
  for (int i = 0; i < NB; i++)
    bpre[i] = *(const bf8*)(Bt + (size_t)(n0 + arow + i * 32) * K + ac * 8);

  const int nkt = K >> 6;
  for (int kt = 0; kt < nkt; ++kt) {
#pragma unroll
    for (int i = 0; i < NA; i++) *(bf8*)&As[arow + i * 32][ac * 8] = apre[i];
#pragma unroll
    for (int i = 0; i < NB; i++) *(bf8*)&Bs[arow + i * 32][ac * 8] = bpre[i];
    __syncthreads();
    if (kt + 1 < nkt) {
      int k0 = (kt + 1) << 6;
#pragma unroll
      for (int i = 0; i < NA; i++)
        apre[i] = *(const bf8*)(A + (size_t)(m0 + arow + i * 32) * K + k0 + ac * 8);
#pragma unroll
      for (int i = 0; i < NB; i++)
        bpre[i] = *(const bf8*)(Bt + (size_t)(n0 + arow + i * 32) * K + k0 + ac * 8);
    }
#pragma unroll
    for (int kk = 0; kk < 2; kk++) {
      bf8 af[MI], bff[NJ];
#pragma unroll
      for (int i = 0; i < MI; i++)
        af[i] = *(const bf8*)&As[wm + i * 16 + lrow][kk * 32 + quad * 8];
#pragma unroll
      for (int j = 0; j < NJ; j++)
        bff[j] = *(const bf8*)&Bs[wn + j * 16 + lrow][kk * 32 + quad * 8];
#pragma unroll
      for (int i = 0; i < MI; i++)
#pragma unroll
        for (int j = 0; j < NJ; j++)
          acc[i][j] = __builtin_amdgcn_mfma_f32_16x16x32_bf16(af[i], bff[j],
                                                              acc[i][j], 0, 0, 0);
    }
    __syncthreads();
  }

#pragma unroll
  for (int j = 0; j < NJ; j++) {
    int col = n0 + wn + j * 16 + lrow;
    float bvv = bias0 ? bias0[col] : 0.f;
#pragma unroll
    for (int i = 0; i < MI; i++) {
#pragma unroll
      for (int r = 0; r < 4; r++) {
        int row = m0 + wm + i * 16 + quad * 4 + r;
        float v = acc[i][j][r] + bvv;
        if (OUT_BF16)
          ((unsigned short*)Cout)[(size_t)row * N + col] = f2bf(v);
        else
          ((float*)Cout)[(size_t)row * N + col] = v;
      }
    }
  }
}

// ------- fused masked cross-attention (R3 LDS structure + sa-carry pipeline) -------
// 10-round model: elapsed/iter ~= MFMA+VALU+DS SUMMED (R10: 2560+3840+3840 ~=
// 10035 measured) -> the barrier locks waves into the same phase, all demand
// the same pipe, pipes serialize. Occupancy doesn't fix it (R10: 4 waves/SIMD,
// same per-unit); free-running doesn't either (R6: L1-BW wall); global-frag
// pipelining dies to reg-sinking (R8, VGPR 96). The remaining lever: INTRA-
// WAVE pipe concurrency with the LDS body (low reg pressure). Carry sa(n)
// across iterations: iter n = {global prefetch K(n+2)/V(n+1)/mask(n+1);
// exp/pack sa(n)->pa [VALU]; re-init sa(n+1) [VALU]; merged MFMA cluster
// PV(n) || scores(n+1) (reads Vbuf[n&1] + Kbuf[(n+1)&1]); stage; barrier}.
// Each wave's 640cy MFMA cluster drains under the next iter's ~900cy VALU ->
// per-SIMD elapsed/iter -> max(pipes) not sum. K staged one tile deeper than
// V. Same ops reordered -> same numerics. launch_bounds(256,2): VGPR cap 128
// (expect ~120; spill would show in WRITE_SIZE).
__global__ __launch_bounds__(256, 2) void attn(const unsigned short* __restrict__ Q,
                                               const unsigned short* __restrict__ K,
                                               const unsigned short* __restrict__ Vt,
                                               const unsigned int* __restrict__ mp,
                                               unsigned short* __restrict__ O) {
  __shared__ unsigned short Ks[2][64][72];
  __shared__ unsigned short Vts[2][64][72];
  const int tid = threadIdx.x;
  const int wave = tid >> 6, lane = tid & 63;
  const int l31 = lane & 31, hi = lane >> 5;
  const int bid = blockIdx.x;
  const int bh = bid & 31, b = bh >> 3, h = bh & 7;
  const int t0 = (bid >> 5) * 128;
  const int wm = wave * 32;
  const int arow = tid >> 3, ac = tid & 7;

  // Q B-frags: lane (t=l31, hi) holds Q[t][c*16 + hi*8 .. +8]
  const unsigned short* Qrow =
      Q + (size_t)(b * Tt + t0 + wm + l31) * Ee + h * 64 + hi * 8;
  bf8 qf[4];
#pragma unroll
  for (int c = 0; c < 4; c++) qf[c] = *(const bf8*)(Qrow + c * 16);

  f16v oacc0, oacc1, dacc;
#pragma unroll
  for (int r = 0; r < 16; r++) {
    oacc0[r] = 0.f;
    oacc1[r] = 0.f;
    dacc[r] = 0.f;
  }
  bf8 ones;
#pragma unroll
  for (int k = 0; k < 8; k++) ones[k] = (short)0x3F80;  // bf16 1.0

  const unsigned short* Kbase = K + (size_t)b * Ssz * Ee + h * 64;
  const unsigned short* Vbase = Vt + (size_t)((b * Hh + h) * 64) * Ssz;
  const unsigned int* mroww = mp + (size_t)(b * Tt + t0 + wm + l31) * 64;

  bf8 kreg[2], vreg[2];

  // ---- prologue ----
  // stage K(0),V(0) -> buf0
#pragma unroll
  for (int i = 0; i < 2; i++) {
    int row = arow + i * 32;
    kreg[i] = *(const bf8*)(Kbase + (size_t)row * Ee + ac * 8);
    vreg[i] = *(const bf8*)(Vbase + (size_t)row * Ssz + ac * 8);
  }
#pragma unroll
  for (int i = 0; i < 2; i++) {
    int row = arow + i * 32;
    *(bf8*)&Ks[0][row][ac * 8] = kreg[i];
    *(bf8*)&Vts[0][row][ac * 8] = vreg[i];
  }
  // load K(1) into regs
#pragma unroll
  for (int i = 0; i < 2; i++) {
    int row = arow + i * 32;
    kreg[i] = *(const bf8*)(Kbase + (size_t)(64 + row) * Ee + ac * 8);
  }
  __syncthreads();  // buf0 visible
  // K(1) -> buf1 (nobody reads buf1 until after the next barrier)
#pragma unroll
  for (int i = 0; i < 2; i++) *(bf8*)&Ks[1][arow + i * 32][ac * 8] = kreg[i];
  // sa-init(0) + scores(0) from Ks[0]
  f16v sa0, sa1;
  {
    const uint2 mw = *(const uint2*)(mroww);
    const unsigned int w0 = mw.x >> (4 * hi);
    const unsigned int w1 = mw.y >> (4 * hi);
#pragma unroll
    for (int r = 0; r < 16; r++) {
      const int sh = (r & 3) + 8 * (r >> 2);
      sa0[r] = ((w0 >> sh) & 1u) ? -1e9f : 0.f;
      sa1[r] = ((w1 >> sh) & 1u) ? -1e9f : 0.f;
    }
#pragma unroll
    for (int c = 0; c < 4; c++) {
      bf8 kf0 = *(const bf8*)&Ks[0][l31][c * 16 + hi * 8];
      bf8 kf1 = *(const bf8*)&Ks[0][32 + l31][c * 16 + hi * 8];
      sa0 = MFMA32(kf0, qf[c], sa0);
      sa1 = MFMA32(kf1, qf[c], sa1);
    }
  }
  __syncthreads();  // K(1) visible; everyone done reading Ks[0]

  // ---- pipelined main loop ----
  for (int n = 0; n < 32; n++) {
    const bool more = (n + 1 < 32);
    // 1. global prefetch: K(n+2), V(n+1), mask(n+1)
    if (n + 2 < 32) {
#pragma unroll
      for (int i = 0; i < 2; i++)
        kreg[i] = *(const bf8*)(Kbase + (size_t)((n + 2) * 64 + arow + i * 32) * Ee + ac * 8);
    }
    if (more) {
#pragma unroll
      for (int i = 0; i < 2; i++)
        vreg[i] = *(const bf8*)(Vbase + (size_t)(arow + i * 32) * Ssz + (n + 1) * 64 + ac * 8);
    }
    uint2 mwn;
    if (more) mwn = *(const uint2*)(mroww + ((n + 1) << 1));
    // 2. exp/pack sa(n) -> pa
    unsigned int X0[8], X1[8];
#pragma unroll
    for (int m = 0; m < 8; m++) {
      X0[m] = PACK2(EXPU(sa0[2 * m]), EXPU(sa0[2 * m + 1]));
      X1[m] = PACK2(EXPU(sa1[2 * m]), EXPU(sa1[2 * m + 1]));
    }
    bf8 pa[4];
#pragma unroll
    for (int c = 0; c < 4; c++) {
      const int m0 = 4 * (c & 1);
      unsigned int a0, a1, a2, a3;
      if (c < 2) {
        a0 = X0[m0]; a1 = X0[m0 + 1]; a2 = X0[m0 + 2]; a3 = X0[m0 + 3];
      } else {
        a0 = X1[m0]; a1 = X1[m0 + 1]; a2 = X1[m0 + 2]; a3 = X1[m0 + 3];
      }
      pl32swap(a0, a2);
      pl32swap(a1, a3);
      u32x4 pdv;
      pdv[0] = a0; pdv[1] = a1; pdv[2] = a2; pdv[3] = a3;
      pa[c] = *(bf8*)&pdv;
    }
    // 3. re-init sa for tile n+1
    if (more) {
      const unsigned int w0 = mwn.x >> (4 * hi);
      const unsigned int w1 = mwn.y >> (4 * hi);
#pragma unroll
      for (int r = 0; r < 16; r++) {
        const int sh = (r & 3) + 8 * (r >> 2);
        sa0[r] = ((w0 >> sh) & 1u) ? -1e9f : 0.f;
        sa1[r] = ((w1 >> sh) & 1u) ? -1e9f : 0.f;
      }
    }
    // 4. merged MFMA cluster: PV(n) from Vts[n&1] || scores(n+1) from Ks[(n+1)&1]
    __builtin_amdgcn_s_setprio(1);
#pragma unroll
    for (int c = 0; c < 4; c++) {
      bf8 vf0 = *(const bf8*)&Vts[n & 1][l31][c * 16 + hi * 8];
      bf8 vf1 = *(const bf8*)&Vts[n & 1][32 + l31][c * 16 + hi * 8];
      dacc = MFMA32(pa[c], ones, dacc);
      oacc0 = MFMA32(pa[c], vf0, oacc0);
      oacc1 = MFMA32(pa[c], vf1, oacc1);
    }
    if (more) {
#pragma unroll
      for (int c = 0; c < 4; c++) {
        bf8 kf0 = *(const bf8*)&Ks[(n + 1) & 1][l31][c * 16 + hi * 8];
        bf8 kf1 = *(const bf8*)&Ks[(n + 1) & 1][32 + l31][c * 16 + hi * 8];
        sa0 = MFMA32(kf0, qf[c], sa0);
        sa1 = MFMA32(kf1, qf[c], sa1);
      }
    }
    __builtin_amdgcn_s_setprio(0);
    // 5. stage: V(n+1) -> Vts[(n+1)&1]; K(n+2) -> Ks[n&1]
    if (more) {
#pragma unroll
      for (int i = 0; i < 2; i++)
        *(bf8*)&Vts[(n + 1) & 1][arow + i * 32][ac * 8] = vreg[i];
    }
    if (n + 2 < 32) {
#pragma unroll
      for (int i = 0; i < 2; i++)
        *(bf8*)&Ks[n & 1][arow + i * 32][ac * 8] = kreg[i];
    }
    __syncthreads();
  }

  // epilogue: O row t = (r&3)+8*(r>>2)+4*hi, col d = dblk*32 + l31
#pragma unroll
  for (int r = 0; r < 16; r++) {
    const int tl = (r & 3) + 8 * (r >> 2) + 4 * hi;
    const float inv = 1.0f / dacc[r];
    const size_t off = (size_t)(b * Tt + t0 + wm + tl) * Ee + h * 64 + l31;
    O[off] = f2bf(oacc0[r] * inv);
    O[off + 32] = f2bf(oacc1[r] * inv);
  }
}

// ---------------- launcher ----------------
extern "C" void kernel_launch(void* const* d_in, const int* in_sizes, int n_in,
                              void* d_out, int out_size, void* d_ws, size_t ws_size,
                              hipStream_t stream) {
  const float* x    = (const float*)d_in[0];
  const float* ctx  = (const float*)d_in[1];
  const int*   mask = (const int*)d_in[2];
  const float* w_in = (const float*)d_in[3];
  const float* b_in = (const float*)d_in[4];
  const float* wq   = (const float*)d_in[5];
  const float* bq   = (const float*)d_in[6];
  const float* wk   = (const float*)d_in[7];
  const float* bk   = (const float*)d_in[8];
  const float* wv   = (const float*)d_in[9];
  const float* bv   = (const float*)d_in[10];
  const float* wo   = (const float*)d_in[11];
  const float* bo   = (const float*)d_in[12];

  const float qsc = 0.04419417382415922f * 1.4426950408889634f;  // E^-0.5 * log2(e)

  unsigned short* ws = (unsigned short*)d_ws;
  unsigned int*   maskp = (unsigned int*)ws;        // [4*2048*64] = 2MB
  unsigned short* wkvb  = ws + 1048576;             // [1024,512]
  unsigned short* wob   = ws + 1572864;             // [256,512]
  unsigned short* wqin  = ws + 1703936;             // [512,256]
  float*          bqinb = (float*)(ws + 1835008);   // [512]
  unsigned short* Qb    = ws + 1836032;             // [8192,512]
  unsigned short* Kb    = ws + 6030336;             // [8192,512]
  unsigned short* Vtb   = ws + 10224640;            // [32,64,2048]
  unsigned short* Ob    = ws + 14418944;            // [8192,512]

  prep<<<688, 256, 0, stream>>>(w_in, b_in, wq, bq, wk, wv, wo,
                                wkvb, wob, wqin, bqinb, qsc);
  qkv<<<2816, 256, 0, stream>>>(x, ctx, wqin, bqinb, wkvb, bk, bv, Qb, Kb, Vtb,
                                mask, maskp);
  attn<<<512, 256, 0, stream>>>(Qb, Kb, Vtb, maskp, Ob);
  gemm_bt<false, 64, 64, 2><<<dim3(128, 4), 256, 0, stream>>>(
      Ob, wob, bo, d_out, 8192, 256, 512);
}

// Round 13
// 225.464 us; speedup vs baseline: 2.8237x; 1.0202x over previous
//
#include <hip/hip_runtime.h>
#include <cstdint>
#include <cstddef>

#define Bb 4
#define Tt 2048
#define Ssz 2048
#define Cc 256
#define Ee 512
#define Hh 8

typedef short bf8 __attribute__((ext_vector_type(8)));
typedef float f4 __attribute__((ext_vector_type(4)));
typedef float f16v __attribute__((ext_vector_type(16)));
typedef unsigned int u32x2 __attribute__((ext_vector_type(2)));
typedef unsigned int u32x4 __attribute__((ext_vector_type(4)));

__device__ __forceinline__ unsigned short f2bf(float x) {
  unsigned int u = __float_as_uint(x);
  u += 0x7fffu + ((u >> 16) & 1u);
  return (unsigned short)(u >> 16);
}

__device__ __forceinline__ bf8 cvt8(float4 a, float4 b) {
  bf8 r;
  r[0] = (short)f2bf(a.x); r[1] = (short)f2bf(a.y);
  r[2] = (short)f2bf(a.z); r[3] = (short)f2bf(a.w);
  r[4] = (short)f2bf(b.x); r[5] = (short)f2bf(b.y);
  r[6] = (short)f2bf(b.z); r[7] = (short)f2bf(b.w);
  return r;
}

// pack two f32 (bit-truncated) into one dword of 2 bf16 via v_perm_b32
#if __has_builtin(__builtin_amdgcn_perm)
#define PACK2(u0, u1) __builtin_amdgcn_perm((u1), (u0), 0x07060302u)
#else
#define PACK2(u0, u1) (((u0) >> 16) | ((u1) & 0xffff0000u))
#endif

#define EXPU(v) __float_as_uint(__builtin_amdgcn_exp2f(v))
#define MFMA32(a, b, c) __builtin_amdgcn_mfma_f32_32x32x16_bf16((a), (b), (c), 0, 0, 0)

// v_permlane32_swap_b32: a.upper32lanes <-> b.lower32lanes (dual result)
__device__ __forceinline__ void pl32swap(unsigned int& a, unsigned int& b) {
#if __has_builtin(__builtin_amdgcn_permlane32_swap)
  u32x2 r = __builtin_amdgcn_permlane32_swap(a, b, false, false);
  a = r[0];
  b = r[1];
#else
  unsigned int ax = (unsigned int)__shfl_xor((int)a, 32);
  unsigned int bx = (unsigned int)__shfl_xor((int)b, 32);
  bool hi = (threadIdx.x & 32) != 0;
  unsigned int an = hi ? bx : a;
  unsigned int bn = hi ? b : ax;
  a = an;
  b = bn;
#endif
}

// ---------------- prep: weight/activation casts + wqin GEMM + bqin ----------------
// bid<512: wk/wv cast; <640: wo cast; <672: wqin; <688: bqin; <1200: x cast;
// <2224: ctx cast. Pre-casting x/ctx to bf16 (same f2bf rounding qkv used
// inline -> bitwise-identical results) removes ~768 VALU cvt ops/thread from
// qkv's K-loop (its m33-style VALU-bound signature) and halves A-side bytes.
__global__ __launch_bounds__(256) void prep(const float* __restrict__ x,
                                            const float* __restrict__ ctx,
                                            const float* __restrict__ w_in,
                                            const float* __restrict__ b_in,
                                            const float* __restrict__ wq,
                                            const float* __restrict__ bq,
                                            const float* __restrict__ wk,
                                            const float* __restrict__ wv,
                                            const float* __restrict__ wo,
                                            unsigned short* __restrict__ wkvb,
                                            unsigned short* __restrict__ wob,
                                            unsigned short* __restrict__ wqin,
                                            float* __restrict__ bqinb,
                                            unsigned short* __restrict__ xb,
                                            unsigned short* __restrict__ ctxb,
                                            float qsc) {
  __shared__ unsigned short sh[128][72];
  const int bid = blockIdx.x, tid = threadIdx.x;
  if (bid < 512) {
    int i = bid * 256 + tid;  // 0..131071
    const float* s = (i < 65536) ? wk : wv;
    int off = (i < 65536) ? i : i - 65536;
    float4 v = ((const float4*)s)[off];
    ushort4 o;
    o.x = f2bf(v.x); o.y = f2bf(v.y); o.z = f2bf(v.z); o.w = f2bf(v.w);
    ((ushort4*)wkvb)[i] = o;
  } else if (bid < 640) {
    int i = (bid - 512) * 256 + tid;  // 0..32767
    float4 v = ((const float4*)wo)[i];
    ushort4 o;
    o.x = f2bf(v.x); o.y = f2bf(v.y); o.z = f2bf(v.z); o.w = f2bf(v.w);
    ((ushort4*)wob)[i] = o;
  } else if (bid < 672) {
    // wqin[512,256] = (qsc*wq)[512,512] . w_in[512,256]
    const int idx = bid - 640;
    const int m0 = (idx & 7) * 64, n0 = (idx >> 3) * 64;
    unsigned short (*As)[72] = (unsigned short (*)[72]) & sh[0][0];
    unsigned short (*Bs)[72] = (unsigned short (*)[72]) & sh[64][0];
    const int wave = tid >> 6, lane = tid & 63;
    const int lrow = lane & 15, quad = lane >> 4;
    const int wm = (wave >> 1) * 32, wn = (wave & 1) * 32;
    const int arow = tid >> 3, ac = tid & 7;
    f4 acc[2][2];
#pragma unroll
    for (int i = 0; i < 2; i++)
#pragma unroll
      for (int j = 0; j < 2; j++) {
        f4 z = {0.f, 0.f, 0.f, 0.f};
        acc[i][j] = z;
      }
    for (int kt = 0; kt < 8; kt++) {
#pragma unroll
      for (int i = 0; i < 2; i++) {
        int row = arow + i * 32;
        const float* src = wq + (size_t)(m0 + row) * Ee + kt * 64 + ac * 8;
        float4 v0 = *(const float4*)src, v1 = *(const float4*)(src + 4);
        bf8 av;
        av[0] = (short)f2bf(v0.x * qsc); av[1] = (short)f2bf(v0.y * qsc);
        av[2] = (short)f2bf(v0.z * qsc); av[3] = (short)f2bf(v0.w * qsc);
        av[4] = (short)f2bf(v1.x * qsc); av[5] = (short)f2bf(v1.y * qsc);
        av[6] = (short)f2bf(v1.z * qsc); av[7] = (short)f2bf(v1.w * qsc);
        *(bf8*)&As[row][ac * 8] = av;
        int c = n0 + row;
        bf8 bv;
#pragma unroll
        for (int k = 0; k < 8; k++)
          bv[k] = (short)f2bf(w_in[(size_t)(kt * 64 + ac * 8 + k) * Cc + c]);
        *(bf8*)&Bs[row][ac * 8] = bv;
      }
      __syncthreads();
#pragma unroll
      for (int kk = 0; kk < 2; kk++) {
        bf8 af[2], bff[2];
#pragma unroll
        for (int i = 0; i < 2; i++) af[i] = *(const bf8*)&As[wm + i * 16 + lrow][kk * 32 + quad * 8];
#pragma unroll
        for (int j = 0; j < 2; j++) bff[j] = *(const bf8*)&Bs[wn + j * 16 + lrow][kk * 32 + quad * 8];
#pragma unroll
        for (int i = 0; i < 2; i++)
#pragma unroll
          for (int j = 0; j < 2; j++)
            acc[i][j] = __builtin_amdgcn_mfma_f32_16x16x32_bf16(af[i], bff[j], acc[i][j], 0, 0, 0);
      }
      __syncthreads();
    }
#pragma unroll
    for (int j = 0; j < 2; j++)
#pragma unroll
      for (int i = 0; i < 2; i++)
#pragma unroll
        for (int r = 0; r < 4; r++)
          wqin[(size_t)(m0 + wm + i * 16 + quad * 4 + r) * Cc + n0 + wn + j * 16 + lrow] =
              f2bf(acc[i][j][r]);
  } else if (bid < 688) {
    const int o = (bid - 672) * 32 + (tid >> 3);
    const int k0 = (tid & 7) * 64;
    float s = 0.f;
#pragma unroll
    for (int i = 0; i < 16; i++) {
      float4 w = *(const float4*)(wq + (size_t)o * Ee + k0 + i * 4);
      float4 bb = *(const float4*)(b_in + k0 + i * 4);
      s += w.x * bb.x + w.y * bb.y + w.z * bb.z + w.w * bb.w;
    }
    s += __shfl_xor(s, 1);
    s += __shfl_xor(s, 2);
    s += __shfl_xor(s, 4);
    if ((tid & 7) == 0) bqinb[o] = (s + bq[o]) * qsc;
  } else if (bid < 1200) {
    // x cast: 2,097,152 floats; 16 floats/thread
    int i = (bid - 688) * 256 + tid;  // 0..131071
    const float4* s = (const float4*)x + (size_t)i * 4;
    float4 a0 = s[0], a1 = s[1], a2 = s[2], a3 = s[3];
    bf8* d = (bf8*)xb + (size_t)i * 2;
    d[0] = cvt8(a0, a1);
    d[1] = cvt8(a2, a3);
  } else {
    // ctx cast: 4,194,304 floats; 16 floats/thread
    int i = (bid - 1200) * 256 + tid;  // 0..262143
    const float4* s = (const float4*)ctx + (size_t)i * 4;
    float4 a0 = s[0], a1 = s[1], a2 = s[2], a3 = s[3];
    bf8* d = (bf8*)ctxb + (size_t)i * 2;
    d[0] = cvt8(a0, a1);
    d[1] = cvt8(a2, a3);
  }
}

// ---------------- Q-GEMM + KV-GEMM + packmask, one dispatch ----------------
// A operands (xb/ctxb) are now pre-cast bf16: staging is a pure 16B copy
// (no per-loop f32->bf16 cvt), A vmem bytes halved, A-prefetch regs halved.
__global__ __launch_bounds__(256) void qkv(const unsigned short* __restrict__ xb,
                                           const unsigned short* __restrict__ ctxb,
                                           const unsigned short* __restrict__ wqin,
                                           const float* __restrict__ bqinb,
                                           const unsigned short* __restrict__ wkv,
                                           const float* __restrict__ bk,
                                           const float* __restrict__ bv,
                                           unsigned short* __restrict__ Qb,
                                           unsigned short* __restrict__ Kb,
                                           unsigned short* __restrict__ Vt,
                                           const int* __restrict__ mask,
                                           unsigned int* __restrict__ mp) {
  __shared__ unsigned short As[128][72];
  __shared__ unsigned short Bs[128][72];
  const int bid = blockIdx.x, tid = threadIdx.x;
  if (bid >= 768) {
    int i = (bid - 768) * 256 + tid;  // 0..524287
    const int4* src = (const int4*)mask + (size_t)i * 8;
    unsigned int w = 0;
#pragma unroll
    for (int k = 0; k < 8; k++) {
      int4 v = src[k];
      w |= (unsigned int)(v.x != 0) << (k * 4);
      w |= (unsigned int)(v.y != 0) << (k * 4 + 1);
      w |= (unsigned int)(v.z != 0) << (k * 4 + 2);
      w |= (unsigned int)(v.w != 0) << (k * 4 + 3);
    }
    mp[i] = w;
    return;
  }
  const bool isQ = bid < 256;
  const int idx = isQ ? bid : bid - 256;
  const int m0 = (idx & 63) * 128;
  const int n0 = (idx >> 6) * 128;
  const int K = isQ ? 256 : 512;
  const unsigned short* A = isQ ? xb : ctxb;
  const unsigned short* Bt = isQ ? wqin : wkv;

  const int wave = tid >> 6, lane = tid & 63;
  const int lrow = lane & 15, quad = lane >> 4;
  const int wm = (wave >> 1) * 64, wn = (wave & 1) * 64;
  const int arow = tid >> 3, ac = tid & 7;

  f4 acc[4][4];
#pragma unroll
  for (int i = 0; i < 4; i++)
#pragma unroll
    for (int j = 0; j < 4; j++) {
      f4 z = {0.f, 0.f, 0.f, 0.f};
      acc[i][j] = z;
    }

  bf8 apre[4], bpre[4];
#pragma unroll
  for (int i = 0; i < 4; i++) {
    apre[i] = *(const bf8*)(A + (size_t)(m0 + arow + i * 32) * K + ac * 8);
    bpre[i] = *(const bf8*)(Bt + (size_t)(n0 + arow + i * 32) * K + ac * 8);
  }

  const int nkt = K >> 6;
  for (int kt = 0; kt < nkt; ++kt) {
#pragma unroll
    for (int i = 0; i < 4; i++) {
      *(bf8*)&As[arow + i * 32][ac * 8] = apre[i];
      *(bf8*)&Bs[arow + i * 32][ac * 8] = bpre[i];
    }
    __syncthreads();
    if (kt + 1 < nkt) {
      int k0 = (kt + 1) << 6;
#pragma unroll
      for (int i = 0; i < 4; i++) {
        apre[i] = *(const bf8*)(A + (size_t)(m0 + arow + i * 32) * K + k0 + ac * 8);
        bpre[i] = *(const bf8*)(Bt + (size_t)(n0 + arow + i * 32) * K + k0 + ac * 8);
      }
    }
#pragma unroll
    for (int kk = 0; kk < 2; kk++) {
      bf8 af[4], bff[4];
#pragma unroll
      for (int i = 0; i < 4; i++)
        af[i] = *(const bf8*)&As[wm + i * 16 + lrow][kk * 32 + quad * 8];
#pragma unroll
      for (int j = 0; j < 4; j++)
        bff[j] = *(const bf8*)&Bs[wn + j * 16 + lrow][kk * 32 + quad * 8];
#pragma unroll
      for (int i = 0; i < 4; i++)
#pragma unroll
        for (int j = 0; j < 4; j++)
          acc[i][j] = __builtin_amdgcn_mfma_f32_16x16x32_bf16(af[i], bff[j],
                                                              acc[i][j], 0, 0, 0);
    }
    __syncthreads();
  }

  if (isQ) {
#pragma unroll
    for (int j = 0; j < 4; j++) {
      int col = n0 + wn + j * 16 + lrow;
      float bvv = bqinb[col];
#pragma unroll
      for (int i = 0; i < 4; i++)
#pragma unroll
        for (int r = 0; r < 4; r++)
          Qb[(size_t)(m0 + wm + i * 16 + quad * 4 + r) * Ee + col] =
              f2bf(acc[i][j][r] + bvv);
    }
  } else if (n0 < 512) {  // K half (uniform per block)
#pragma unroll
    for (int j = 0; j < 4; j++) {
      int col = n0 + wn + j * 16 + lrow;
      float bvv = bk[col];
#pragma unroll
      for (int i = 0; i < 4; i++)
#pragma unroll
        for (int r = 0; r < 4; r++)
          Kb[(size_t)(m0 + wm + i * 16 + quad * 4 + r) * Ee + col] =
              f2bf(acc[i][j][r] + bvv);
    }
  } else {  // V half -> transposed store
#pragma unroll
    for (int j = 0; j < 4; j++) {
      int d = n0 - 512 + wn + j * 16 + lrow;
      int h = d >> 6, dd = d & 63;
      float bvv = bv[d];
#pragma unroll
      for (int i = 0; i < 4; i++) {
        int tok = m0 + wm + i * 16 + quad * 4;  // 4 consecutive tokens
        int b = tok >> 11, sl = tok & 2047;
        ushort4 pk;
        pk.x = f2bf(acc[i][j][0] + bvv);
        pk.y = f2bf(acc[i][j][1] + bvv);
        pk.z = f2bf(acc[i][j][2] + bvv);
        pk.w = f2bf(acc[i][j][3] + bvv);
        *(ushort4*)(Vt + (size_t)((b * Hh + h) * 64 + dd) * Ssz + sl) = pk;
      }
    }
  }
}

// ---------------- GEMM: C[M,N] = A[M,K]*Bt[N,K]^T + bias (bf16 A) ----------------
template <bool OUT_BF16, int BM, int BN, int WGM>
__global__ __launch_bounds__(256) void gemm_bt(const unsigned short* __restrict__ A,
                                               const unsigned short* __restrict__ Bt,
                                               const float* __restrict__ bias0,
                                               void* __restrict__ Cout,
                                               int M, int N, int K) {
  constexpr int WGN = 4 / WGM;
  constexpr int MI = BM / (WGM * 16);
  constexpr int NJ = BN / (WGN * 16);
  constexpr int NA = BM / 32;
  constexpr int NB = BN / 32;
  __shared__ unsigned short As[BM][72];
  __shared__ unsigned short Bs[BN][72];
  const int tid = threadIdx.x;
  const int wave = tid >> 6, lane = tid & 63;
  const int lrow = lane & 15, quad = lane >> 4;
  const int wm = (wave / WGN) * (BM / WGM);
  const int wn = (wave % WGN) * (BN / WGN);
  const int m0 = blockIdx.x * BM, n0 = blockIdx.y * BN;
  const int arow = tid >> 3, ac = tid & 7;

  f4 acc[MI][NJ];
#pragma unroll
  for (int i = 0; i < MI; i++)
#pragma unroll
    for (int j = 0; j < NJ; j++) {
      f4 z = {0.f, 0.f, 0.f, 0.f};
      acc[i][j] = z;
    }

  bf8 apre[NA], bpre[NB];
#pragma unroll
  for (int i = 0; i < NA; i++)
    apre[i] = *(const bf8*)(A + (size_t)(m0 + arow + i * 32) * K + ac * 8);
#pragma unroll
  for (int i = 0; i < NB; i++)
    bpre[i] = *(const bf8*)(Bt + (size_t)(n0 + arow + i * 32) * K + ac * 8);

  const int nkt = K >> 6;
  for (int kt = 0; kt < nkt; ++kt) {
#pragma unroll
    for (int i = 0; i < NA; i++) *(bf8*)&As[arow + i * 32][ac * 8] = apre[i];
#pragma unroll
    for (int i = 0; i < NB; i++) *(bf8*)&Bs[arow + i * 32][ac * 8] = bpre[i];
    __syncthreads();
    if (kt + 1 < nkt) {
      int k0 = (kt + 1) << 6;
#pragma unroll
      for (int i = 0; i < NA; i++)
        apre[i] = *(const bf8*)(A + (size_t)(m0 + arow + i * 32) * K + k0 + ac * 8);
#pragma unroll
      for (int i = 0; i < NB; i++)
        bpre[i] = *(const bf8*)(Bt + (size_t)(n0 + arow + i * 32) * K + k0 + ac * 8);
    }
#pragma unroll
    for (int kk = 0; kk < 2; kk++) {
      bf8 af[MI], bff[NJ];
#pragma unroll
      for (int i = 0; i < MI; i++)
        af[i] = *(const bf8*)&As[wm + i * 16 + lrow][kk * 32 + quad * 8];
#pragma unroll
      for (int j = 0; j < NJ; j++)
        bff[j] = *(const bf8*)&Bs[wn + j * 16 + lrow][kk * 32 + quad * 8];
#pragma unroll
      for (int i = 0; i < MI; i++)
#pragma unroll
        for (int j = 0; j < NJ; j++)
          acc[i][j] = __builtin_amdgcn_mfma_f32_16x16x32_bf16(af[i], bff[j],
                                                              acc[i][j], 0, 0, 0);
    }
    __syncthreads();
  }

#pragma unroll
  for (int j = 0; j < NJ; j++) {
    int col = n0 + wn + j * 16 + lrow;
    float bvv = bias0 ? bias0[col] : 0.f;
#pragma unroll
    for (int i = 0; i < MI; i++) {
#pragma unroll
      for (int r = 0; r < 4; r++) {
        int row = m0 + wm + i * 16 + quad * 4 + r;
        float v = acc[i][j][r] + bvv;
        if (OUT_BF16)
          ((unsigned short*)Cout)[(size_t)row * N + col] = f2bf(v);
        else
          ((float*)Cout)[(size_t)row * N + col] = v;
      }
    }
  }
}

// ------- fused masked cross-attention (R11: R3 LDS structure + sa-carry pipeline) --
// Settled at ~59us after 11 rounds (confirmed floor of this structure: per-iter
// ~4425cyc, no pipe >45%, occupancy/ILP/pipelining all explored). Kept as-is.
__global__ __launch_bounds__(256, 2) void attn(const unsigned short* __restrict__ Q,
                                               const unsigned short* __restrict__ K,
                                               const unsigned short* __restrict__ Vt,
                                               const unsigned int* __restrict__ mp,
                                               unsigned short* __restrict__ O) {
  __shared__ unsigned short Ks[2][64][72];
  __shared__ unsigned short Vts[2][64][72];
  const int tid = threadIdx.x;
  const int wave = tid >> 6, lane = tid & 63;
  const int l31 = lane & 31, hi = lane >> 5;
  const int bid = blockIdx.x;
  const int bh = bid & 31, b = bh >> 3, h = bh & 7;
  const int t0 = (bid >> 5) * 128;
  const int wm = wave * 32;
  const int arow = tid >> 3, ac = tid & 7;

  // Q B-frags: lane (t=l31, hi) holds Q[t][c*16 + hi*8 .. +8]
  const unsigned short* Qrow =
      Q + (size_t)(b * Tt + t0 + wm + l31) * Ee + h * 64 + hi * 8;
  bf8 qf[4];
#pragma unroll
  for (int c = 0; c < 4; c++) qf[c] = *(const bf8*)(Qrow + c * 16);

  f16v oacc0, oacc1, dacc;
#pragma unroll
  for (int r = 0; r < 16; r++) {
    oacc0[r] = 0.f;
    oacc1[r] = 0.f;
    dacc[r] = 0.f;
  }
  bf8 ones;
#pragma unroll
  for (int k = 0; k < 8; k++) ones[k] = (short)0x3F80;  // bf16 1.0

  const unsigned short* Kbase = K + (size_t)b * Ssz * Ee + h * 64;
  const unsigned short* Vbase = Vt + (size_t)((b * Hh + h) * 64) * Ssz;
  const unsigned int* mroww = mp + (size_t)(b * Tt + t0 + wm + l31) * 64;

  bf8 kreg[2], vreg[2];

  // ---- prologue ----
#pragma unroll
  for (int i = 0; i < 2; i++) {
    int row = arow + i * 32;
    kreg[i] = *(const bf8*)(Kbase + (size_t)row * Ee + ac * 8);
    vreg[i] = *(const bf8*)(Vbase + (size_t)row * Ssz + ac * 8);
  }
#pragma unroll
  for (int i = 0; i < 2; i++) {
    int row = arow + i * 32;
    *(bf8*)&Ks[0][row][ac * 8] = kreg[i];
    *(bf8*)&Vts[0][row][ac * 8] = vreg[i];
  }
#pragma unroll
  for (int i = 0; i < 2; i++) {
    int row = arow + i * 32;
    kreg[i] = *(const bf8*)(Kbase + (size_t)(64 + row) * Ee + ac * 8);
  }
  __syncthreads();  // buf0 visible
#pragma unroll
  for (int i = 0; i < 2; i++) *(bf8*)&Ks[1][arow + i * 32][ac * 8] = kreg[i];
  f16v sa0, sa1;
  {
    const uint2 mw = *(const uint2*)(mroww);
    const unsigned int w0 = mw.x >> (4 * hi);
    const unsigned int w1 = mw.y >> (4 * hi);
#pragma unroll
    for (int r = 0; r < 16; r++) {
      const int sh = (r & 3) + 8 * (r >> 2);
      sa0[r] = ((w0 >> sh) & 1u) ? -1e9f : 0.f;
      sa1[r] = ((w1 >> sh) & 1u) ? -1e9f : 0.f;
    }
#pragma unroll
    for (int c = 0; c < 4; c++) {
      bf8 kf0 = *(const bf8*)&Ks[0][l31][c * 16 + hi * 8];
      bf8 kf1 = *(const bf8*)&Ks[0][32 + l31][c * 16 + hi * 8];
      sa0 = MFMA32(kf0, qf[c], sa0);
      sa1 = MFMA32(kf1, qf[c], sa1);
    }
  }
  __syncthreads();  // K(1) visible; everyone done reading Ks[0]

  // ---- pipelined main loop ----
  for (int n = 0; n < 32; n++) {
    const bool more = (n + 1 < 32);
    if (n + 2 < 32) {
#pragma unroll
      for (int i = 0; i < 2; i++)
        kreg[i] = *(const bf8*)(Kbase + (size_t)((n + 2) * 64 + arow + i * 32) * Ee + ac * 8);
    }
    if (more) {
#pragma unroll
      for (int i = 0; i < 2; i++)
        vreg[i] = *(const bf8*)(Vbase + (size_t)(arow + i * 32) * Ssz + (n + 1) * 64 + ac * 8);
    }
    uint2 mwn;
    if (more) mwn = *(const uint2*)(mroww + ((n + 1) << 1));
    unsigned int X0[8], X1[8];
#pragma unroll
    for (int m = 0; m < 8; m++) {
      X0[m] = PACK2(EXPU(sa0[2 * m]), EXPU(sa0[2 * m + 1]));
      X1[m] = PACK2(EXPU(sa1[2 * m]), EXPU(sa1[2 * m + 1]));
    }
    bf8 pa[4];
#pragma unroll
    for (int c = 0; c < 4; c++) {
      const int m0 = 4 * (c & 1);
      unsigned int a0, a1, a2, a3;
      if (c < 2) {
        a0 = X0[m0]; a1 = X0[m0 + 1]; a2 = X0[m0 + 2]; a3 = X0[m0 + 3];
      } else {
        a0 = X1[m0]; a1 = X1[m0 + 1]; a2 = X1[m0 + 2]; a3 = X1[m0 + 3];
      }
      pl32swap(a0, a2);
      pl32swap(a1, a3);
      u32x4 pdv;
      pdv[0] = a0; pdv[1] = a1; pdv[2] = a2; pdv[3] = a3;
      pa[c] = *(bf8*)&pdv;
    }
    if (more) {
      const unsigned int w0 = mwn.x >> (4 * hi);
      const unsigned int w1 = mwn.y >> (4 * hi);
#pragma unroll
      for (int r = 0; r < 16; r++) {
        const int sh = (r & 3) + 8 * (r >> 2);
        sa0[r] = ((w0 >> sh) & 1u) ? -1e9f : 0.f;
        sa1[r] = ((w1 >> sh) & 1u) ? -1e9f : 0.f;
      }
    }
    __builtin_amdgcn_s_setprio(1);
#pragma unroll
    for (int c = 0; c < 4; c++) {
      bf8 vf0 = *(const bf8*)&Vts[n & 1][l31][c * 16 + hi * 8];
      bf8 vf1 = *(const bf8*)&Vts[n & 1][32 + l31][c * 16 + hi * 8];
      dacc = MFMA32(pa[c], ones, dacc);
      oacc0 = MFMA32(pa[c], vf0, oacc0);
      oacc1 = MFMA32(pa[c], vf1, oacc1);
    }
    if (more) {
#pragma unroll
      for (int c = 0; c < 4; c++) {
        bf8 kf0 = *(const bf8*)&Ks[(n + 1) & 1][l31][c * 16 + hi * 8];
        bf8 kf1 = *(const bf8*)&Ks[(n + 1) & 1][32 + l31][c * 16 + hi * 8];
        sa0 = MFMA32(kf0, qf[c], sa0);
        sa1 = MFMA32(kf1, qf[c], sa1);
      }
    }
    __builtin_amdgcn_s_setprio(0);
    if (more) {
#pragma unroll
      for (int i = 0; i < 2; i++)
        *(bf8*)&Vts[(n + 1) & 1][arow + i * 32][ac * 8] = vreg[i];
    }
    if (n + 2 < 32) {
#pragma unroll
      for (int i = 0; i < 2; i++)
        *(bf8*)&Ks[n & 1][arow + i * 32][ac * 8] = kreg[i];
    }
    __syncthreads();
  }

  // epilogue: O row t = (r&3)+8*(r>>2)+4*hi, col d = dblk*32 + l31
#pragma unroll
  for (int r = 0; r < 16; r++) {
    const int tl = (r & 3) + 8 * (r >> 2) + 4 * hi;
    const float inv = 1.0f / dacc[r];
    const size_t off = (size_t)(b * Tt + t0 + wm + tl) * Ee + h * 64 + l31;
    O[off] = f2bf(oacc0[r] * inv);
    O[off + 32] = f2bf(oacc1[r] * inv);
  }
}

// ---------------- launcher ----------------
extern "C" void kernel_launch(void* const* d_in, const int* in_sizes, int n_in,
                              void* d_out, int out_size, void* d_ws, size_t ws_size,
                              hipStream_t stream) {
  const float* x    = (const float*)d_in[0];
  const float* ctx  = (const float*)d_in[1];
  const int*   mask = (const int*)d_in[2];
  const float* w_in = (const float*)d_in[3];
  const float* b_in = (const float*)d_in[4];
  const float* wq   = (const float*)d_in[5];
  const float* bq   = (const float*)d_in[6];
  const float* wk   = (const float*)d_in[7];
  const float* bk   = (const float*)d_in[8];
  const float* wv   = (const float*)d_in[9];
  const float* bv   = (const float*)d_in[10];
  const float* wo   = (const float*)d_in[11];
  const float* bo   = (const float*)d_in[12];

  const float qsc = 0.04419417382415922f * 1.4426950408889634f;  // E^-0.5 * log2(e)

  unsigned short* ws = (unsigned short*)d_ws;
  unsigned int*   maskp = (unsigned int*)ws;        // [4*2048*64] = 2MB
  unsigned short* wkvb  = ws + 1048576;             // [1024,512]
  unsigned short* wob   = ws + 1572864;             // [256,512]
  unsigned short* wqin  = ws + 1703936;             // [512,256]
  float*          bqinb = (float*)(ws + 1835008);   // [512]
  unsigned short* Qb    = ws + 1836032;             // [8192,512]
  unsigned short* Kb    = ws + 6030336;             // [8192,512]
  unsigned short* Vtb   = ws + 10224640;            // [32,64,2048]
  unsigned short* Ob    = ws + 14418944;            // [8192,512]
  // xb aliases Ob's slot: xb is dead before attn writes Ob (sequential stream)
  unsigned short* xb    = ws + 14418944;            // [8192,256] bf16
  unsigned short* ctxb  = ws + 18613248;            // [8192,512] bf16

  prep<<<2224, 256, 0, stream>>>(x, ctx, w_in, b_in, wq, bq, wk, wv, wo,
                                 wkvb, wob, wqin, bqinb, xb, ctxb, qsc);
  qkv<<<2816, 256, 0, stream>>>(xb, ctxb, wqin, bqinb, wkvb, bk, bv, Qb, Kb, Vtb,
                                mask, maskp);
  attn<<<512, 256, 0, stream>>>(Qb, Kb, Vtb, maskp, Ob);
  gemm_bt<false, 64, 64, 2><<<dim3(128, 4), 256, 0, stream>>>(
      Ob, wob, bo, d_out, 8192, 256, 512);
}